// Round 3
// baseline (742.335 us; speedup 1.0000x reference)
//
#include <hip/hip_runtime.h>
#include <hip/hip_bf16.h>
#include <math.h>

// ---------------------------------------------------------------------------
// NodeMLPModel: edge MLP (GEMM+BN+SELU+GEMM) -> scatter-mean -> node MLP.
// bf16 MFMA 16x16x32, f32 accum.
// Round-3 structure:
//   * Xa = x @ W1a[:128] computed per-NODE (gemmX), stored bf16 in packed
//     C-fragment layout Xap[v][lr*8+n0]  (col = n0*16+lr).
//   * Edge pipeline processed in CSR (dest-sorted) order: gemm1s does the
//     K=64 ea-part MFMA + gathers Xap[row] in epilogue (+fused BN stats),
//     writes T1 in sorted order. gemm2s reads T1 sequentially, run-merged
//     atomicAdd into f32 S (L2-local, few distinct nodes per block).
//   * No segsum kernel; gemm3 reads S/max(cnt,1).
// Fragment layout (m89/m91-verified):
//   A: lane holds A[lane&15][8*(lane>>4)+j]
//   B: lane holds B[8*(lane>>4)+j][lane&15]
//   D: lane holds D[4*(lane>>4)+r][lane&15]
// ---------------------------------------------------------------------------

typedef __attribute__((ext_vector_type(8))) short bfrag;
typedef __attribute__((ext_vector_type(4))) float f32x4;

#define N_EDGES 800000
#define N_NODES 100000

static __device__ __forceinline__ short f2bf(float f) {
    union { float f; unsigned u; } v; v.f = f;
    unsigned r = (v.u + 0x7FFFu + ((v.u >> 16) & 1u)) >> 16;  // RNE
    return (short)r;
}
static __device__ __forceinline__ float bf2f(short h) {
    union { unsigned u; float f; } v;
    v.u = ((unsigned)(unsigned short)h) << 16;
    return v.f;
}

static __device__ __forceinline__ bfrag load8f_bf(const float* __restrict__ p) {
    float4 a = *(const float4*)p;
    float4 b = *(const float4*)(p + 4);
    bfrag r;
    r[0] = f2bf(a.x); r[1] = f2bf(a.y); r[2] = f2bf(a.z); r[3] = f2bf(a.w);
    r[4] = f2bf(b.x); r[5] = f2bf(b.y); r[6] = f2bf(b.z); r[7] = f2bf(b.w);
    return r;
}

// Pack W[K][128] f32 row-major -> bf16 fragment order:
// Wp[(((kb*128 + n)*4 + g)*8 + j)] = W[kb*32 + g*8 + j][n]
__global__ void pack_w(const float* __restrict__ W, short* __restrict__ Wp, int K) {
    int idx = blockIdx.x * 256 + threadIdx.x;
    if (idx >= K * 128) return;
    int k = idx >> 7, n = idx & 127;
    int kb = k >> 5, g = (k >> 3) & 3, j = k & 7;
    Wp[(((size_t)kb * 128 + n) * 4 + g) * 8 + j] = f2bf(W[idx]);
}

// ----------------------------- CSR build -----------------------------------
__global__ void hist_k(const int* __restrict__ col, int* __restrict__ cnt, int E) {
    int i = blockIdx.x * 256 + threadIdx.x;
    if (i < E) atomicAdd(&cnt[col[i]], 1);
}

__global__ void scan1(const int* __restrict__ cnt, int* __restrict__ off,
                      int* __restrict__ bsum, int N) {
    __shared__ int ls[1024];
    int i = blockIdx.x * 1024 + threadIdx.x;
    int v = (i < N) ? cnt[i] : 0;
    ls[threadIdx.x] = v;
    __syncthreads();
    for (int d = 1; d < 1024; d <<= 1) {
        int t = (threadIdx.x >= d) ? ls[threadIdx.x - d] : 0;
        __syncthreads();
        ls[threadIdx.x] += t;
        __syncthreads();
    }
    if (i < N) off[i] = ls[threadIdx.x] - v;  // block-local exclusive
    if (threadIdx.x == 1023) bsum[blockIdx.x] = ls[1023];
}

__global__ void scan2(const int* __restrict__ bsum, int* __restrict__ boff, int NB) {
    __shared__ int ls[128];
    int v = (threadIdx.x < NB) ? bsum[threadIdx.x] : 0;
    ls[threadIdx.x] = v;
    __syncthreads();
    for (int d = 1; d < 128; d <<= 1) {
        int t = (threadIdx.x >= d) ? ls[threadIdx.x - d] : 0;
        __syncthreads();
        ls[threadIdx.x] += t;
        __syncthreads();
    }
    if (threadIdx.x < NB) boff[threadIdx.x] = ls[threadIdx.x] - v;  // exclusive
}

__global__ void scan3(int* __restrict__ off, const int* __restrict__ boff, int N) {
    int i = blockIdx.x * 1024 + threadIdx.x;
    if (i < N) off[i] += boff[blockIdx.x];
}

// Consumes OFF. Writes perm (edge id), cols (dest), rows (src) in sorted order.
__global__ void fill_k(const int* __restrict__ col, const int* __restrict__ row,
                       int* __restrict__ off, int* __restrict__ perm,
                       int* __restrict__ colS, int* __restrict__ rowS, int E) {
    int e = blockIdx.x * 256 + threadIdx.x;
    if (e < E) {
        int c = col[e];
        int q = atomicAdd(&off[c], 1);
        perm[q] = e;
        colS[q] = c;
        rowS[q] = row[e];
    }
}

// ---------------------------------------------------------------------------
// gemmX: Xap = packed bf16 of (x @ W1a[:128,:])   [N_NODES rows]
// Packed layout: Xap[v*128 + lr*8 + n0] = Xa[v][n0*16+lr]
__global__ __launch_bounds__(256) void gemmX(
    const float* __restrict__ x, const short* __restrict__ Wp,
    short* __restrict__ Xap, int N)
{
    const int lane = threadIdx.x & 63, wave = threadIdx.x >> 6;
    const int m0 = blockIdx.x * 128 + wave * 32;
    if (m0 >= N) return;  // N % 32 == 0
    const int lr = lane & 15, lg = lane >> 4;
    const int v0 = m0 + lr, v1 = m0 + 16 + lr;

    f32x4 acc[2][8];
#pragma unroll
    for (int t = 0; t < 2; ++t)
#pragma unroll
        for (int n = 0; n < 8; ++n) acc[t][n] = (f32x4){0.f, 0.f, 0.f, 0.f};

#pragma unroll
    for (int kb = 0; kb < 4; ++kb) {
        bfrag a0 = load8f_bf(x + (size_t)v0 * 128 + kb * 32 + lg * 8);
        bfrag a1 = load8f_bf(x + (size_t)v1 * 128 + kb * 32 + lg * 8);
        const short* wb = Wp + (size_t)kb * 4096;
#pragma unroll
        for (int n0 = 0; n0 < 8; ++n0) {
            bfrag b = *(const bfrag*)(wb + ((n0 * 16 + lr) * 4 + lg) * 8);
            acc[0][n0] = __builtin_amdgcn_mfma_f32_16x16x32_bf16(a0, b, acc[0][n0], 0, 0, 0);
            acc[1][n0] = __builtin_amdgcn_mfma_f32_16x16x32_bf16(a1, b, acc[1][n0], 0, 0, 0);
        }
    }
#pragma unroll
    for (int t = 0; t < 2; ++t) {
        const int rbase = m0 + t * 16 + lg * 4;
#pragma unroll
        for (int r = 0; r < 4; ++r) {
            bfrag o;
#pragma unroll
            for (int n0 = 0; n0 < 8; ++n0) o[n0] = f2bf(acc[t][n0][r]);
            *(bfrag*)(Xap + (size_t)(rbase + r) * 128 + lr * 8) = o;
        }
    }
}

// ---------------------------------------------------------------------------
// gemm1s: T1[p] = ea[perm[p]] @ W1a[128:192] + Xa[rowS[p]]   (sorted order)
// fused column sum/sumsq -> stats
__global__ __launch_bounds__(256) void gemm1s(
    const float* __restrict__ ea, const int* __restrict__ perm,
    const int* __restrict__ rowS, const short* __restrict__ Wp,
    const short* __restrict__ Xap, short* __restrict__ T1,
    float* __restrict__ stats, int E)
{
    const int lane = threadIdx.x & 63, wave = threadIdx.x >> 6;
    const int m0 = blockIdx.x * 128 + wave * 32;   // E % 128 == 0
    const int lr = lane & 15, lg = lane >> 4;
    __shared__ float ls[256];
    ls[threadIdx.x] = 0.f;
    __syncthreads();

    const int e0 = perm[m0 + lr], e1 = perm[m0 + 16 + lr];
    const float* er0 = ea + (size_t)e0 * 64;
    const float* er1 = ea + (size_t)e1 * 64;

    f32x4 acc[2][8];
#pragma unroll
    for (int t = 0; t < 2; ++t)
#pragma unroll
        for (int n = 0; n < 8; ++n) acc[t][n] = (f32x4){0.f, 0.f, 0.f, 0.f};

#pragma unroll
    for (int kb = 0; kb < 2; ++kb) {
        bfrag a0 = load8f_bf(er0 + kb * 32 + lg * 8);
        bfrag a1 = load8f_bf(er1 + kb * 32 + lg * 8);
        const short* wb = Wp + (size_t)kb * 4096;
#pragma unroll
        for (int n0 = 0; n0 < 8; ++n0) {
            bfrag b = *(const bfrag*)(wb + ((n0 * 16 + lr) * 4 + lg) * 8);
            acc[0][n0] = __builtin_amdgcn_mfma_f32_16x16x32_bf16(a0, b, acc[0][n0], 0, 0, 0);
            acc[1][n0] = __builtin_amdgcn_mfma_f32_16x16x32_bf16(a1, b, acc[1][n0], 0, 0, 0);
        }
    }
    // epilogue: gather packed Xa rows, add, stats, store
#pragma unroll
    for (int t = 0; t < 2; ++t) {
        const int rbase = m0 + t * 16 + lg * 4;
        bfrag xa[4];
#pragma unroll
        for (int r = 0; r < 4; ++r)
            xa[r] = *(const bfrag*)(Xap + (size_t)rowS[rbase + r] * 128 + lr * 8);
#pragma unroll
        for (int n0 = 0; n0 < 8; ++n0) {
            const int c = n0 * 16 + lr;
            float p = 0.f, q = 0.f;
#pragma unroll
            for (int r = 0; r < 4; ++r) {
                float v = acc[t][n0][r] + bf2f(xa[r][n0]);
                p += v; q += v * v;
                T1[(size_t)(rbase + r) * 128 + c] = f2bf(v);
            }
            p += __shfl_xor(p, 16); p += __shfl_xor(p, 32);
            q += __shfl_xor(q, 16); q += __shfl_xor(q, 32);
            if (lg == 0) { atomicAdd(&ls[c], p); atomicAdd(&ls[128 + c], q); }
        }
    }
    __syncthreads();
    atomicAdd(&stats[threadIdx.x], ls[threadIdx.x]);
}

// scale/shift from stats: bnp[0:128]=scale, bnp[128:256]=shift
__global__ void bn_final(const float* __restrict__ stats, const float* __restrict__ g,
                         const float* __restrict__ be, float* __restrict__ bnp, float invR)
{
    int j = threadIdx.x;
    float mean = stats[j] * invR;
    float var = stats[128 + j] * invR - mean * mean;
    float sc = g[j] * rsqrtf(var + 1e-5f);
    bnp[j] = sc;
    bnp[128 + j] = be[j] - mean * sc;
}

static __device__ __forceinline__ float selu_f(float v) {
    return v > 0.f ? 1.0507009873554805f * v : 1.7580993408473766f * expm1f(v);
}

// gemm2s: selu(BN(T1)) @ W1b + b1b, run-merged atomicAdd into S (f32) by colS
__global__ __launch_bounds__(256) void gemm2s(
    const short* __restrict__ T1, const float* __restrict__ bnp,
    const short* __restrict__ Wp, const float* __restrict__ b1b,
    const int* __restrict__ colS, float* __restrict__ S, int E)
{
    const int lane = threadIdx.x & 63, wave = threadIdx.x >> 6;
    const int m0 = blockIdx.x * 128 + wave * 32;
    const int lr = lane & 15, lg = lane >> 4;
    const int e0 = m0 + lr, e1 = m0 + 16 + lr;

    f32x4 acc[2][8];
#pragma unroll
    for (int n0 = 0; n0 < 8; ++n0) {
        float bias = b1b[n0 * 16 + lr];
        acc[0][n0] = (f32x4){bias, bias, bias, bias};
        acc[1][n0] = (f32x4){bias, bias, bias, bias};
    }
#pragma unroll
    for (int kb = 0; kb < 4; ++kb) {
        const int koff = kb * 32 + lg * 8;
        float4 sc0 = *(const float4*)(bnp + koff);
        float4 sc1 = *(const float4*)(bnp + koff + 4);
        float4 sh0 = *(const float4*)(bnp + 128 + koff);
        float4 sh1 = *(const float4*)(bnp + 128 + koff + 4);
        float scl[8] = {sc0.x, sc0.y, sc0.z, sc0.w, sc1.x, sc1.y, sc1.z, sc1.w};
        float shf[8] = {sh0.x, sh0.y, sh0.z, sh0.w, sh1.x, sh1.y, sh1.z, sh1.w};
        bfrag r0 = *(const bfrag*)(T1 + (size_t)e0 * 128 + koff);
        bfrag r1 = *(const bfrag*)(T1 + (size_t)e1 * 128 + koff);
        bfrag a0, a1;
#pragma unroll
        for (int j = 0; j < 8; ++j) {
            a0[j] = f2bf(selu_f(bf2f(r0[j]) * scl[j] + shf[j]));
            a1[j] = f2bf(selu_f(bf2f(r1[j]) * scl[j] + shf[j]));
        }
        const short* wb = Wp + (size_t)kb * 4096;
#pragma unroll
        for (int n0 = 0; n0 < 8; ++n0) {
            bfrag b = *(const bfrag*)(wb + ((n0 * 16 + lr) * 4 + lg) * 8);
            acc[0][n0] = __builtin_amdgcn_mfma_f32_16x16x32_bf16(a0, b, acc[0][n0], 0, 0, 0);
            acc[1][n0] = __builtin_amdgcn_mfma_f32_16x16x32_bf16(a1, b, acc[1][n0], 0, 0, 0);
        }
    }
    // epilogue: cols are sorted -> merge equal-col runs within each 4-row group
#pragma unroll
    for (int t = 0; t < 2; ++t) {
        const int rbase = m0 + t * 16 + lg * 4;
        int c4[4];
#pragma unroll
        for (int r = 0; r < 4; ++r) c4[r] = colS[rbase + r];
#pragma unroll
        for (int n0 = 0; n0 < 8; ++n0) {
            const int c = n0 * 16 + lr;
            int cc = c4[0];
            float v = acc[t][n0][0];
#pragma unroll
            for (int r = 1; r < 4; ++r) {
                if (c4[r] == cc) v += acc[t][n0][r];
                else {
                    atomicAdd(&S[(size_t)cc * 128 + c], v);
                    cc = c4[r]; v = acc[t][n0][r];
                }
            }
            atomicAdd(&S[(size_t)cc * 128 + c], v);
        }
    }
}

// Node GEMM1: T2 = concat(x, S/max(cnt,1), u[batch]) @ W2a ; fused stats
__global__ __launch_bounds__(256) void gemm3_node(
    const float* __restrict__ x, const float* __restrict__ S, const int* __restrict__ cnti,
    const float* __restrict__ u, const int* __restrict__ batch,
    const short* __restrict__ Wp, short* __restrict__ T2,
    float* __restrict__ stats, int N)
{
    const int lane = threadIdx.x & 63, wave = threadIdx.x >> 6;
    const int m0 = blockIdx.x * 128 + wave * 32;
    const bool active = (m0 < N);   // N % 32 == 0
    const int lr = lane & 15, lg = lane >> 4;
    __shared__ float ls[256];
    ls[threadIdx.x] = 0.f;
    __syncthreads();

    const int v0 = active ? m0 + lr : 0, v1 = active ? m0 + 16 + lr : 0;
    const float inv0 = 1.0f / fmaxf((float)cnti[v0], 1.0f);
    const float inv1 = 1.0f / fmaxf((float)cnti[v1], 1.0f);
    const float* u0 = u + (size_t)batch[v0] * 128;
    const float* u1 = u + (size_t)batch[v1] * 128;

    f32x4 acc[2][8];
#pragma unroll
    for (int t = 0; t < 2; ++t)
#pragma unroll
        for (int n = 0; n < 8; ++n) acc[t][n] = (f32x4){0.f, 0.f, 0.f, 0.f};

    if (active) {
#pragma unroll
        for (int kb = 0; kb < 12; ++kb) {
            bfrag a0, a1;
            if (kb >= 4 && kb < 8) {
                const float* p0 = S + (size_t)v0 * 128 + (kb - 4) * 32 + lg * 8;
                const float* p1 = S + (size_t)v1 * 128 + (kb - 4) * 32 + lg * 8;
                float4 x0a = *(const float4*)p0, x0b = *(const float4*)(p0 + 4);
                float4 x1a = *(const float4*)p1, x1b = *(const float4*)(p1 + 4);
                a0[0] = f2bf(x0a.x * inv0); a0[1] = f2bf(x0a.y * inv0);
                a0[2] = f2bf(x0a.z * inv0); a0[3] = f2bf(x0a.w * inv0);
                a0[4] = f2bf(x0b.x * inv0); a0[5] = f2bf(x0b.y * inv0);
                a0[6] = f2bf(x0b.z * inv0); a0[7] = f2bf(x0b.w * inv0);
                a1[0] = f2bf(x1a.x * inv1); a1[1] = f2bf(x1a.y * inv1);
                a1[2] = f2bf(x1a.z * inv1); a1[3] = f2bf(x1a.w * inv1);
                a1[4] = f2bf(x1b.x * inv1); a1[5] = f2bf(x1b.y * inv1);
                a1[6] = f2bf(x1b.z * inv1); a1[7] = f2bf(x1b.w * inv1);
            } else {
                const float *p0, *p1;
                if (kb < 4) {
                    p0 = x + (size_t)v0 * 128 + kb * 32 + lg * 8;
                    p1 = x + (size_t)v1 * 128 + kb * 32 + lg * 8;
                } else {
                    p0 = u0 + (kb - 8) * 32 + lg * 8;
                    p1 = u1 + (kb - 8) * 32 + lg * 8;
                }
                a0 = load8f_bf(p0);
                a1 = load8f_bf(p1);
            }
            const short* wb = Wp + (size_t)kb * 4096;
#pragma unroll
            for (int n0 = 0; n0 < 8; ++n0) {
                bfrag b = *(const bfrag*)(wb + ((n0 * 16 + lr) * 4 + lg) * 8);
                acc[0][n0] = __builtin_amdgcn_mfma_f32_16x16x32_bf16(a0, b, acc[0][n0], 0, 0, 0);
                acc[1][n0] = __builtin_amdgcn_mfma_f32_16x16x32_bf16(a1, b, acc[1][n0], 0, 0, 0);
            }
        }
#pragma unroll
        for (int n0 = 0; n0 < 8; ++n0) {
            const int c = n0 * 16 + lr;
            float p = 0.f, q = 0.f;
#pragma unroll
            for (int t = 0; t < 2; ++t) {
                const int rbase = m0 + t * 16 + lg * 4;
#pragma unroll
                for (int r = 0; r < 4; ++r) {
                    float v = acc[t][n0][r];
                    p += v; q += v * v;
                    T2[(size_t)(rbase + r) * 128 + c] = f2bf(v);
                }
            }
            p += __shfl_xor(p, 16); p += __shfl_xor(p, 32);
            q += __shfl_xor(q, 16); q += __shfl_xor(q, 32);
            if (lg == 0) { atomicAdd(&ls[c], p); atomicAdd(&ls[128 + c], q); }
        }
    }
    __syncthreads();
    atomicAdd(&stats[threadIdx.x], ls[threadIdx.x]);
}

// Node GEMM2: out = selu(BN(T2)) @ W2b + b2b   (f32 output)
__global__ __launch_bounds__(256) void gemm4_node(
    const short* __restrict__ T2, const float* __restrict__ bnp,
    const short* __restrict__ Wp, const float* __restrict__ b2b,
    float* __restrict__ out, int N)
{
    const int lane = threadIdx.x & 63, wave = threadIdx.x >> 6;
    const int m0 = blockIdx.x * 128 + wave * 32;
    if (m0 >= N) return;   // N % 32 == 0
    const int lr = lane & 15, lg = lane >> 4;
    const int e0 = m0 + lr, e1 = m0 + 16 + lr;

    f32x4 acc[2][8];
#pragma unroll
    for (int n0 = 0; n0 < 8; ++n0) {
        float bias = b2b[n0 * 16 + lr];
        acc[0][n0] = (f32x4){bias, bias, bias, bias};
        acc[1][n0] = (f32x4){bias, bias, bias, bias};
    }
#pragma unroll
    for (int kb = 0; kb < 4; ++kb) {
        const int koff = kb * 32 + lg * 8;
        float4 sc0 = *(const float4*)(bnp + koff);
        float4 sc1 = *(const float4*)(bnp + koff + 4);
        float4 sh0 = *(const float4*)(bnp + 128 + koff);
        float4 sh1 = *(const float4*)(bnp + 128 + koff + 4);
        float scl[8] = {sc0.x, sc0.y, sc0.z, sc0.w, sc1.x, sc1.y, sc1.z, sc1.w};
        float shf[8] = {sh0.x, sh0.y, sh0.z, sh0.w, sh1.x, sh1.y, sh1.z, sh1.w};
        bfrag r0 = *(const bfrag*)(T2 + (size_t)e0 * 128 + koff);
        bfrag r1 = *(const bfrag*)(T2 + (size_t)e1 * 128 + koff);
        bfrag a0, a1;
#pragma unroll
        for (int j = 0; j < 8; ++j) {
            a0[j] = f2bf(selu_f(bf2f(r0[j]) * scl[j] + shf[j]));
            a1[j] = f2bf(selu_f(bf2f(r1[j]) * scl[j] + shf[j]));
        }
        const short* wb = Wp + (size_t)kb * 4096;
#pragma unroll
        for (int n0 = 0; n0 < 8; ++n0) {
            bfrag b = *(const bfrag*)(wb + ((n0 * 16 + lr) * 4 + lg) * 8);
            acc[0][n0] = __builtin_amdgcn_mfma_f32_16x16x32_bf16(a0, b, acc[0][n0], 0, 0, 0);
            acc[1][n0] = __builtin_amdgcn_mfma_f32_16x16x32_bf16(a1, b, acc[1][n0], 0, 0, 0);
        }
    }
#pragma unroll
    for (int t = 0; t < 2; ++t) {
        const int rbase = m0 + t * 16 + lg * 4;
#pragma unroll
        for (int n0 = 0; n0 < 8; ++n0) {
            const int c = n0 * 16 + lr;
#pragma unroll
            for (int r = 0; r < 4; ++r)
                out[(size_t)(rbase + r) * 128 + c] = acc[t][n0][r];
        }
    }
}

// ---------------------------------------------------------------------------
// Workspace layout (bytes):
//   0       Wp1x 32768 | 32768 Wp1e 16384 | 49152 Wp1b 32768
//   81920   Wp2a 98304 | 180224 Wp2b 32768
//   212992  stats1 1024 | 214016 bnp1 1024 | 215040 stats2 1024 | 216064 bnp2 1024
//   217088  CNTi 400000 | 617088 OFF 400000 (consumed by fill_k)
//   1017088 BSUM 1024   | 1018112 BOFF 1024
//   1019136 COLS 3200000                       -> 4219136
//   4219136 REGION2 (51200000):                -> 55419136
//     phase1: Xap 25600000 @4219136 | PERM 3200000 @29819136 | ROWS 3200000 @33019136
//     phase2: S f32 100000x128 @4219136 (memset after gemm1s)
//   55419136 REGION1 (204800000):              -> 260219136
//     phase1: T1 bf16 800000x128
//     phase2: T2 bf16 100000x128 (overlay; T1 dead after gemm2s)
//   total: 260219136
// ---------------------------------------------------------------------------
extern "C" void kernel_launch(void* const* d_in, const int* in_sizes, int n_in,
                              void* d_out, int out_size, void* d_ws, size_t ws_size,
                              hipStream_t stream)
{
    const float* x   = (const float*)d_in[0];
    const float* ea  = (const float*)d_in[1];
    const float* u   = (const float*)d_in[2];
    const float* W1a = (const float*)d_in[3];
    // d_in[4] = b1a: cancels in BN
    const float* g1  = (const float*)d_in[5];
    const float* be1 = (const float*)d_in[6];
    const float* W1b = (const float*)d_in[7];
    const float* b1b = (const float*)d_in[8];
    const float* W2a = (const float*)d_in[9];
    // d_in[10] = b2a: cancels in BN
    const float* g2  = (const float*)d_in[11];
    const float* be2 = (const float*)d_in[12];
    const float* W2b = (const float*)d_in[13];
    const float* b2b = (const float*)d_in[14];
    const int* ei    = (const int*)d_in[15];
    const int* rowI  = ei;
    const int* colI  = ei + N_EDGES;
    const int* batch = (const int*)d_in[16];
    float* out = (float*)d_out;

    if (ws_size < 260619136ull) return;

    char* ws = (char*)d_ws;
    short* Wp1x   = (short*)(ws + 0);
    short* Wp1e   = (short*)(ws + 32768);
    short* Wp1b   = (short*)(ws + 49152);
    short* Wp2a   = (short*)(ws + 81920);
    short* Wp2b   = (short*)(ws + 180224);
    float* stats1 = (float*)(ws + 212992);
    float* bnp1   = (float*)(ws + 214016);
    float* stats2 = (float*)(ws + 215040);
    float* bnp2   = (float*)(ws + 216064);
    int*   CNTi   = (int*)(ws + 217088);
    int*   OFF    = (int*)(ws + 617088);
    int*   BSUM   = (int*)(ws + 1017088);
    int*   BOFF   = (int*)(ws + 1018112);
    int*   COLS   = (int*)(ws + 1019136);
    short* Xap    = (short*)(ws + 4219136);
    int*   PERM   = (int*)(ws + 29819136ull);
    int*   ROWS   = (int*)(ws + 33019136ull);
    float* S      = (float*)(ws + 4219136);       // overlays Xap/PERM/ROWS (phase 2)
    short* T1     = (short*)(ws + 55419136ull);
    short* T2     = (short*)(ws + 55419136ull);   // overlays T1 (phase 2)

    hipMemsetAsync(stats1, 0, 4096, stream);      // stats1,bnp1,stats2,bnp2
    hipMemsetAsync(CNTi, 0, 400000, stream);

    pack_w<<<64, 256, 0, stream>>>(W1a, Wp1x, 128);
    pack_w<<<32, 256, 0, stream>>>(W1a + 128 * 128, Wp1e, 64);
    pack_w<<<64, 256, 0, stream>>>(W1b, Wp1b, 128);
    pack_w<<<192, 256, 0, stream>>>(W2a, Wp2a, 384);
    pack_w<<<64, 256, 0, stream>>>(W2b, Wp2b, 128);

    // CSR build (dest-sorted edge order)
    hist_k<<<(N_EDGES + 255) / 256, 256, 0, stream>>>(colI, CNTi, N_EDGES);
    scan1<<<98, 1024, 0, stream>>>(CNTi, OFF, BSUM, N_NODES);
    scan2<<<1, 128, 0, stream>>>(BSUM, BOFF, 98);
    scan3<<<98, 1024, 0, stream>>>(OFF, BOFF, N_NODES);
    fill_k<<<(N_EDGES + 255) / 256, 256, 0, stream>>>(colI, rowI, OFF, PERM, COLS, ROWS, N_EDGES);

    // node-side half of edge layer 1
    gemmX<<<(N_NODES + 127) / 128, 256, 0, stream>>>(x, Wp1x, Xap, N_NODES);

    // edge MLP layer 1 (sorted order) + stats
    gemm1s<<<N_EDGES / 128, 256, 0, stream>>>(ea, PERM, ROWS, Wp1e, Xap, T1, stats1, N_EDGES);
    bn_final<<<1, 128, 0, stream>>>(stats1, g1, be1, bnp1, 1.0f / (float)N_EDGES);

    // S overlays Xap/PERM/ROWS -- zero it only now
    hipMemsetAsync(S, 0, (size_t)N_NODES * 128 * 4, stream);

    // edge MLP layer 2 + scatter-sum
    gemm2s<<<N_EDGES / 128, 256, 0, stream>>>(T1, bnp1, Wp1b, b1b, COLS, S, N_EDGES);

    // node MLP
    gemm3_node<<<(N_NODES + 127) / 128, 256, 0, stream>>>(x, S, CNTi, u, batch, Wp2a, T2, stats2, N_NODES);
    bn_final<<<1, 128, 0, stream>>>(stats2, g2, be2, bnp2, 1.0f / (float)N_NODES);
    gemm4_node<<<(N_NODES + 127) / 128, 256, 0, stream>>>(T2, bnp2, Wp2b, b2b, out, N_NODES);
}

// Round 4
// 567.733 us; speedup vs baseline: 1.3075x; 1.3075x over previous
//
#include <hip/hip_runtime.h>
#include <hip/hip_bf16.h>
#include <math.h>

// ---------------------------------------------------------------------------
// NodeMLPModel: edge MLP (GEMM+BN+SELU+GEMM) -> scatter-mean -> node MLP.
// Round-4 structure:
//   * gemmX: Xa = x @ W1a[:128] per NODE, packed bf16 (C-fragment-friendly).
//   * gemm1n (natural edge order): T1 = ea @ W1a[128:] + Xa[row], fused BN
//     stats. ea read sequential; Xap gathered as full 256B rows.
//   * segsel: Agg[v] = mean_{e in bucket(v)} selu(BN1(T1[e])) -- segmented
//     sum via CSR perm, one wave per node, NO atomics, no MFMA.
//   * Fold: agg @ W2a_mid = Agg @ (W1b@W2a_mid) + (deg>0)*(b1b@W2a_mid).
//     W2a' middle block and cb precomputed in f32 on device.
//   * gemm3: T2 = [x, Agg, u[batch]] @ W2a' + flag*cb, fused stats.
//   * gemm4: out = selu(BN2(T2)) @ W2b + b2b.
// Fragment layout (m89/m91-verified):
//   A: lane holds A[lane&15][8*(lane>>4)+j]
//   B: lane holds B[8*(lane>>4)+j][lane&15]
//   D: lane holds D[4*(lane>>4)+r][lane&15]
// ---------------------------------------------------------------------------

typedef __attribute__((ext_vector_type(8))) short bfrag;
typedef __attribute__((ext_vector_type(4))) float f32x4;

#define N_EDGES 800000
#define N_NODES 100000

static __device__ __forceinline__ short f2bf(float f) {
    union { float f; unsigned u; } v; v.f = f;
    unsigned r = (v.u + 0x7FFFu + ((v.u >> 16) & 1u)) >> 16;  // RNE
    return (short)r;
}
static __device__ __forceinline__ float bf2f(short h) {
    union { unsigned u; float f; } v;
    v.u = ((unsigned)(unsigned short)h) << 16;
    return v.f;
}
static __device__ __forceinline__ unsigned pack2(float lo, float hi) {
    return ((unsigned)(unsigned short)f2bf(lo)) | (((unsigned)(unsigned short)f2bf(hi)) << 16);
}

static __device__ __forceinline__ bfrag load8f_bf(const float* __restrict__ p) {
    float4 a = *(const float4*)p;
    float4 b = *(const float4*)(p + 4);
    bfrag r;
    r[0] = f2bf(a.x); r[1] = f2bf(a.y); r[2] = f2bf(a.z); r[3] = f2bf(a.w);
    r[4] = f2bf(b.x); r[5] = f2bf(b.y); r[6] = f2bf(b.z); r[7] = f2bf(b.w);
    return r;
}

static __device__ __forceinline__ float selu_f(float v) {
    return v > 0.f ? 1.0507009873554805f * v
                   : 1.7580993408473766f * (__expf(v) - 1.0f);
}

// Pack W[K][128] f32 row-major -> bf16 fragment order:
// Wp[(((kb*128 + n)*4 + g)*8 + j)] = W[kb*32 + g*8 + j][n]
__global__ void pack_w(const float* __restrict__ W, short* __restrict__ Wp, int K) {
    int idx = blockIdx.x * 256 + threadIdx.x;
    if (idx >= K * 128) return;
    int k = idx >> 7, n = idx & 127;
    int kb = k >> 5, g = (k >> 3) & 3, j = k & 7;
    Wp[(((size_t)kb * 128 + n) * 4 + g) * 8 + j] = f2bf(W[idx]);
}

// Wf[k][c] = sum_j W1b[k][j] * W2a[128+j][c]   (fold W1b into node GEMM)
__global__ void fold_w(const float* __restrict__ W1b, const float* __restrict__ W2a,
                       float* __restrict__ Wf) {
    int idx = blockIdx.x * 256 + threadIdx.x;   // 16384
    int k = idx >> 7, c = idx & 127;
    float s = 0.f;
    for (int j = 0; j < 128; ++j) s += W1b[k * 128 + j] * W2a[(size_t)(128 + j) * 128 + c];
    Wf[idx] = s;
}

// cb[c] = sum_j b1b[j] * W2a[128+j][c]
__global__ void fold_b(const float* __restrict__ b1b, const float* __restrict__ W2a,
                       float* __restrict__ cb) {
    int c = threadIdx.x;
    float s = 0.f;
    for (int j = 0; j < 128; ++j) s += b1b[j] * W2a[(size_t)(128 + j) * 128 + c];
    cb[c] = s;
}

// ----------------------------- CSR build -----------------------------------
__global__ void hist_k(const int* __restrict__ col, int* __restrict__ cnt, int E) {
    int i = blockIdx.x * 256 + threadIdx.x;
    if (i < E) atomicAdd(&cnt[col[i]], 1);
}

__global__ void scan1(const int* __restrict__ cnt, int* __restrict__ off,
                      int* __restrict__ bsum, int N) {
    __shared__ int ls[1024];
    int i = blockIdx.x * 1024 + threadIdx.x;
    int v = (i < N) ? cnt[i] : 0;
    ls[threadIdx.x] = v;
    __syncthreads();
    for (int d = 1; d < 1024; d <<= 1) {
        int t = (threadIdx.x >= d) ? ls[threadIdx.x - d] : 0;
        __syncthreads();
        ls[threadIdx.x] += t;
        __syncthreads();
    }
    if (i < N) off[i] = ls[threadIdx.x] - v;
    if (threadIdx.x == 1023) bsum[blockIdx.x] = ls[1023];
}

__global__ void scan2(const int* __restrict__ bsum, int* __restrict__ boff, int NB) {
    __shared__ int ls[128];
    int v = (threadIdx.x < NB) ? bsum[threadIdx.x] : 0;
    ls[threadIdx.x] = v;
    __syncthreads();
    for (int d = 1; d < 128; d <<= 1) {
        int t = (threadIdx.x >= d) ? ls[threadIdx.x - d] : 0;
        __syncthreads();
        ls[threadIdx.x] += t;
        __syncthreads();
    }
    if (threadIdx.x < NB) boff[threadIdx.x] = ls[threadIdx.x] - v;
}

__global__ void scan3(int* __restrict__ off, const int* __restrict__ boff, int N) {
    int i = blockIdx.x * 1024 + threadIdx.x;
    if (i < N) off[i] += boff[blockIdx.x];
}

// Consumes OFF (becomes end offsets: beg = OFF[v]-CNTi[v]).
__global__ void fill_k(const int* __restrict__ col, int* __restrict__ off,
                       int* __restrict__ perm, int E) {
    int e = blockIdx.x * 256 + threadIdx.x;
    if (e < E) {
        int q = atomicAdd(&off[col[e]], 1);
        perm[q] = e;
    }
}

// ---------------------------------------------------------------------------
// gemmX: Xap = packed bf16 of (x @ W1a[:128,:])
// Layout: Xap[v*128 + lr*8 + n0] = Xa[v][n0*16+lr]
__global__ __launch_bounds__(256) void gemmX(
    const float* __restrict__ x, const short* __restrict__ Wp,
    short* __restrict__ Xap, int N)
{
    const int lane = threadIdx.x & 63, wave = threadIdx.x >> 6;
    const int m0 = blockIdx.x * 128 + wave * 32;
    if (m0 >= N) return;  // N % 32 == 0
    const int lr = lane & 15, lg = lane >> 4;
    const int v0 = m0 + lr, v1 = m0 + 16 + lr;

    f32x4 acc[2][8];
#pragma unroll
    for (int t = 0; t < 2; ++t)
#pragma unroll
        for (int n = 0; n < 8; ++n) acc[t][n] = (f32x4){0.f, 0.f, 0.f, 0.f};

#pragma unroll
    for (int kb = 0; kb < 4; ++kb) {
        bfrag a0 = load8f_bf(x + (size_t)v0 * 128 + kb * 32 + lg * 8);
        bfrag a1 = load8f_bf(x + (size_t)v1 * 128 + kb * 32 + lg * 8);
        const short* wb = Wp + (size_t)kb * 4096;
#pragma unroll
        for (int n0 = 0; n0 < 8; ++n0) {
            bfrag b = *(const bfrag*)(wb + ((n0 * 16 + lr) * 4 + lg) * 8);
            acc[0][n0] = __builtin_amdgcn_mfma_f32_16x16x32_bf16(a0, b, acc[0][n0], 0, 0, 0);
            acc[1][n0] = __builtin_amdgcn_mfma_f32_16x16x32_bf16(a1, b, acc[1][n0], 0, 0, 0);
        }
    }
#pragma unroll
    for (int t = 0; t < 2; ++t) {
        const int rbase = m0 + t * 16 + lg * 4;
#pragma unroll
        for (int r = 0; r < 4; ++r) {
            bfrag o;
#pragma unroll
            for (int n0 = 0; n0 < 8; ++n0) o[n0] = f2bf(acc[t][n0][r]);
            *(bfrag*)(Xap + (size_t)(rbase + r) * 128 + lr * 8) = o;
        }
    }
}

// ---------------------------------------------------------------------------
// gemm1n: T1[e] = ea[e] @ W1a[128:192] + Xa[row[e]]  (natural order)
// fused column sum/sumsq -> stats
__global__ __launch_bounds__(256) void gemm1n(
    const float* __restrict__ ea, const int* __restrict__ rowI,
    const short* __restrict__ Wp, const short* __restrict__ Xap,
    short* __restrict__ T1, float* __restrict__ stats, int E)
{
    const int lane = threadIdx.x & 63, wave = threadIdx.x >> 6;
    const int m0 = blockIdx.x * 128 + wave * 32;   // E % 128 == 0
    const int lr = lane & 15, lg = lane >> 4;
    __shared__ float ls[256];
    ls[threadIdx.x] = 0.f;
    __syncthreads();

    const float* er0 = ea + (size_t)(m0 + lr) * 64;
    const float* er1 = ea + (size_t)(m0 + 16 + lr) * 64;

    f32x4 acc[2][8];
#pragma unroll
    for (int t = 0; t < 2; ++t)
#pragma unroll
        for (int n = 0; n < 8; ++n) acc[t][n] = (f32x4){0.f, 0.f, 0.f, 0.f};

#pragma unroll
    for (int kb = 0; kb < 2; ++kb) {
        bfrag a0 = load8f_bf(er0 + kb * 32 + lg * 8);
        bfrag a1 = load8f_bf(er1 + kb * 32 + lg * 8);
        const short* wb = Wp + (size_t)kb * 4096;
#pragma unroll
        for (int n0 = 0; n0 < 8; ++n0) {
            bfrag b = *(const bfrag*)(wb + ((n0 * 16 + lr) * 4 + lg) * 8);
            acc[0][n0] = __builtin_amdgcn_mfma_f32_16x16x32_bf16(a0, b, acc[0][n0], 0, 0, 0);
            acc[1][n0] = __builtin_amdgcn_mfma_f32_16x16x32_bf16(a1, b, acc[1][n0], 0, 0, 0);
        }
    }
    // epilogue: gather packed Xa rows, add, stats, store
#pragma unroll
    for (int t = 0; t < 2; ++t) {
        const int rbase = m0 + t * 16 + lg * 4;
        bfrag xa[4];
#pragma unroll
        for (int r = 0; r < 4; ++r)
            xa[r] = *(const bfrag*)(Xap + (size_t)rowI[rbase + r] * 128 + lr * 8);
#pragma unroll
        for (int n0 = 0; n0 < 8; ++n0) {
            const int c = n0 * 16 + lr;
            float p = 0.f, q = 0.f;
#pragma unroll
            for (int r = 0; r < 4; ++r) {
                float v = acc[t][n0][r] + bf2f(xa[r][n0]);
                p += v; q += v * v;
                T1[(size_t)(rbase + r) * 128 + c] = f2bf(v);
            }
            p += __shfl_xor(p, 16); p += __shfl_xor(p, 32);
            q += __shfl_xor(q, 16); q += __shfl_xor(q, 32);
            if (lg == 0) { atomicAdd(&ls[c], p); atomicAdd(&ls[128 + c], q); }
        }
    }
    __syncthreads();
    atomicAdd(&stats[threadIdx.x], ls[threadIdx.x]);
}

// scale/shift from stats: bnp[0:128]=scale, bnp[128:256]=shift
__global__ void bn_final(const float* __restrict__ stats, const float* __restrict__ g,
                         const float* __restrict__ be, float* __restrict__ bnp, float invR)
{
    int j = threadIdx.x;
    float mean = stats[j] * invR;
    float var = stats[128 + j] * invR - mean * mean;
    float sc = g[j] * rsqrtf(var + 1e-5f);
    bnp[j] = sc;
    bnp[128 + j] = be[j] - mean * sc;
}

// ---------------------------------------------------------------------------
// segsel: Aggm[v] = (1/max(deg,1)) * sum_{e in bucket(v)} selu(BN1(T1[e]))
// One wave per node (grid-stride). Lane covers cols {2*lane, 2*lane+1}.
__global__ __launch_bounds__(256) void segsel(
    const short* __restrict__ T1, const float* __restrict__ bnp,
    const int* __restrict__ OFF, const int* __restrict__ CNTi,
    const int* __restrict__ perm, short* __restrict__ Aggm, int N)
{
    const int lane = threadIdx.x & 63;
    const int wid = blockIdx.x * 4 + (threadIdx.x >> 6);
    const int nw = gridDim.x * 4;
    const float sc0 = bnp[2 * lane],       sc1 = bnp[2 * lane + 1];
    const float sh0 = bnp[128 + 2 * lane], sh1 = bnp[128 + 2 * lane + 1];

    for (int v = wid; v < N; v += nw) {
        const int cnt = CNTi[v];
        const int beg = OFF[v] - cnt;   // fill_k advanced OFF to end
        float a0 = 0.f, a1 = 0.f;
        int j = 0;
        for (; j + 4 <= cnt; j += 4) {
            int e0 = perm[beg + j], e1 = perm[beg + j + 1];
            int e2 = perm[beg + j + 2], e3 = perm[beg + j + 3];
            unsigned w0 = *(const unsigned*)(T1 + (size_t)e0 * 128 + lane * 2);
            unsigned w1 = *(const unsigned*)(T1 + (size_t)e1 * 128 + lane * 2);
            unsigned w2 = *(const unsigned*)(T1 + (size_t)e2 * 128 + lane * 2);
            unsigned w3 = *(const unsigned*)(T1 + (size_t)e3 * 128 + lane * 2);
            a0 += selu_f(sc0 * bf2f((short)(w0 & 0xffff)) + sh0);
            a1 += selu_f(sc1 * bf2f((short)(w0 >> 16)) + sh1);
            a0 += selu_f(sc0 * bf2f((short)(w1 & 0xffff)) + sh0);
            a1 += selu_f(sc1 * bf2f((short)(w1 >> 16)) + sh1);
            a0 += selu_f(sc0 * bf2f((short)(w2 & 0xffff)) + sh0);
            a1 += selu_f(sc1 * bf2f((short)(w2 >> 16)) + sh1);
            a0 += selu_f(sc0 * bf2f((short)(w3 & 0xffff)) + sh0);
            a1 += selu_f(sc1 * bf2f((short)(w3 >> 16)) + sh1);
        }
        for (; j < cnt; ++j) {
            int e = perm[beg + j];
            unsigned w = *(const unsigned*)(T1 + (size_t)e * 128 + lane * 2);
            a0 += selu_f(sc0 * bf2f((short)(w & 0xffff)) + sh0);
            a1 += selu_f(sc1 * bf2f((short)(w >> 16)) + sh1);
        }
        const float inv = 1.0f / fmaxf((float)cnt, 1.0f);
        *(unsigned*)(Aggm + (size_t)v * 128 + lane * 2) = pack2(a0 * inv, a1 * inv);
    }
}

// ---------------------------------------------------------------------------
// gemm3: T2 = [x, Aggm, u[batch]] @ W2a' + (deg>0)*cb ; fused stats
__global__ __launch_bounds__(256) void gemm3_node(
    const float* __restrict__ x, const short* __restrict__ Aggm,
    const float* __restrict__ u, const int* __restrict__ batch,
    const int* __restrict__ CNTi, const float* __restrict__ cb,
    const short* __restrict__ Wp, short* __restrict__ T2,
    float* __restrict__ stats, int N)
{
    const int lane = threadIdx.x & 63, wave = threadIdx.x >> 6;
    const int m0 = blockIdx.x * 128 + wave * 32;
    const bool active = (m0 < N);   // N % 32 == 0
    const int lr = lane & 15, lg = lane >> 4;
    __shared__ float ls[256];
    ls[threadIdx.x] = 0.f;
    __syncthreads();

    const int v0 = active ? m0 + lr : 0, v1 = active ? m0 + 16 + lr : 0;
    const float* u0 = u + (size_t)batch[v0] * 128;
    const float* u1 = u + (size_t)batch[v1] * 128;

    f32x4 acc[2][8];
#pragma unroll
    for (int t = 0; t < 2; ++t)
#pragma unroll
        for (int n = 0; n < 8; ++n) acc[t][n] = (f32x4){0.f, 0.f, 0.f, 0.f};

    if (active) {
#pragma unroll
        for (int kb = 0; kb < 12; ++kb) {
            bfrag a0, a1;
            if (kb >= 4 && kb < 8) {
                a0 = *(const bfrag*)(Aggm + (size_t)v0 * 128 + (kb - 4) * 32 + lg * 8);
                a1 = *(const bfrag*)(Aggm + (size_t)v1 * 128 + (kb - 4) * 32 + lg * 8);
            } else {
                const float *p0, *p1;
                if (kb < 4) {
                    p0 = x + (size_t)v0 * 128 + kb * 32 + lg * 8;
                    p1 = x + (size_t)v1 * 128 + kb * 32 + lg * 8;
                } else {
                    p0 = u0 + (kb - 8) * 32 + lg * 8;
                    p1 = u1 + (kb - 8) * 32 + lg * 8;
                }
                a0 = load8f_bf(p0);
                a1 = load8f_bf(p1);
            }
            const short* wb = Wp + (size_t)kb * 4096;
#pragma unroll
            for (int n0 = 0; n0 < 8; ++n0) {
                bfrag b = *(const bfrag*)(wb + ((n0 * 16 + lr) * 4 + lg) * 8);
                acc[0][n0] = __builtin_amdgcn_mfma_f32_16x16x32_bf16(a0, b, acc[0][n0], 0, 0, 0);
                acc[1][n0] = __builtin_amdgcn_mfma_f32_16x16x32_bf16(a1, b, acc[1][n0], 0, 0, 0);
            }
        }
        // epilogue: + flag*cb, stats, store
        float cbl[8];
#pragma unroll
        for (int n0 = 0; n0 < 8; ++n0) cbl[n0] = cb[n0 * 16 + lr];
#pragma unroll
        for (int t = 0; t < 2; ++t) {
            const int rbase = m0 + t * 16 + lg * 4;
            float fl[4];
#pragma unroll
            for (int r = 0; r < 4; ++r) fl[r] = (CNTi[rbase + r] > 0) ? 1.f : 0.f;
#pragma unroll
            for (int n0 = 0; n0 < 8; ++n0) {
                const int c = n0 * 16 + lr;
                float p = 0.f, q = 0.f;
#pragma unroll
                for (int r = 0; r < 4; ++r) {
                    float v = acc[t][n0][r] + fl[r] * cbl[n0];
                    p += v; q += v * v;
                    T2[(size_t)(rbase + r) * 128 + c] = f2bf(v);
                }
                p += __shfl_xor(p, 16); p += __shfl_xor(p, 32);
                q += __shfl_xor(q, 16); q += __shfl_xor(q, 32);
                if (lg == 0) { atomicAdd(&ls[c], p); atomicAdd(&ls[128 + c], q); }
            }
        }
    }
    __syncthreads();
    atomicAdd(&stats[threadIdx.x], ls[threadIdx.x]);
}

// Node GEMM2: out = selu(BN(T2)) @ W2b + b2b   (f32 output)
__global__ __launch_bounds__(256) void gemm4_node(
    const short* __restrict__ T2, const float* __restrict__ bnp,
    const short* __restrict__ Wp, const float* __restrict__ b2b,
    float* __restrict__ out, int N)
{
    const int lane = threadIdx.x & 63, wave = threadIdx.x >> 6;
    const int m0 = blockIdx.x * 128 + wave * 32;
    if (m0 >= N) return;   // N % 32 == 0
    const int lr = lane & 15, lg = lane >> 4;
    const int e0 = m0 + lr, e1 = m0 + 16 + lr;

    f32x4 acc[2][8];
#pragma unroll
    for (int n0 = 0; n0 < 8; ++n0) {
        float bias = b2b[n0 * 16 + lr];
        acc[0][n0] = (f32x4){bias, bias, bias, bias};
        acc[1][n0] = (f32x4){bias, bias, bias, bias};
    }
#pragma unroll
    for (int kb = 0; kb < 4; ++kb) {
        const int koff = kb * 32 + lg * 8;
        float4 sc0 = *(const float4*)(bnp + koff);
        float4 sc1 = *(const float4*)(bnp + koff + 4);
        float4 sh0 = *(const float4*)(bnp + 128 + koff);
        float4 sh1 = *(const float4*)(bnp + 128 + koff + 4);
        float scl[8] = {sc0.x, sc0.y, sc0.z, sc0.w, sc1.x, sc1.y, sc1.z, sc1.w};
        float shf[8] = {sh0.x, sh0.y, sh0.z, sh0.w, sh1.x, sh1.y, sh1.z, sh1.w};
        bfrag r0 = *(const bfrag*)(T2 + (size_t)e0 * 128 + koff);
        bfrag r1 = *(const bfrag*)(T2 + (size_t)e1 * 128 + koff);
        bfrag a0, a1;
#pragma unroll
        for (int j = 0; j < 8; ++j) {
            a0[j] = f2bf(selu_f(bf2f(r0[j]) * scl[j] + shf[j]));
            a1[j] = f2bf(selu_f(bf2f(r1[j]) * scl[j] + shf[j]));
        }
        const short* wb = Wp + (size_t)kb * 4096;
#pragma unroll
        for (int n0 = 0; n0 < 8; ++n0) {
            bfrag b = *(const bfrag*)(wb + ((n0 * 16 + lr) * 4 + lg) * 8);
            acc[0][n0] = __builtin_amdgcn_mfma_f32_16x16x32_bf16(a0, b, acc[0][n0], 0, 0, 0);
            acc[1][n0] = __builtin_amdgcn_mfma_f32_16x16x32_bf16(a1, b, acc[1][n0], 0, 0, 0);
        }
    }
#pragma unroll
    for (int t = 0; t < 2; ++t) {
        const int rbase = m0 + t * 16 + lg * 4;
#pragma unroll
        for (int n0 = 0; n0 < 8; ++n0) {
            const int c = n0 * 16 + lr;
#pragma unroll
            for (int r = 0; r < 4; ++r)
                out[(size_t)(rbase + r) * 128 + c] = acc[t][n0][r];
        }
    }
}

// ---------------------------------------------------------------------------
// Workspace layout (bytes):
//   0        Wp1x 32768  | 32768 Wp1e 16384 | 49152 Wp2a 98304 | 147456 Wp2b 32768
//   180224   Wf 65536    | 245760 cb 512
//   246272   stats1 1024 | 247296 bnp1 1024 | 248320 stats2 1024 | 249344 bnp2 1024
//   250368   CNTi 400000 | 650368 OFF 400000
//   1050368  BSUM 1024   | 1051392 BOFF 1024
//   1052416  PERM 3200000
//   4252416  Aggm bf16 100000x128 (25600000)
//   29852416 Xap bf16 100000x128 (25600000)  [phase2: T2 overlays]
//   55452416 T1 bf16 800000x128 (204800000)
//   total: 260252416
// ---------------------------------------------------------------------------
extern "C" void kernel_launch(void* const* d_in, const int* in_sizes, int n_in,
                              void* d_out, int out_size, void* d_ws, size_t ws_size,
                              hipStream_t stream)
{
    const float* x   = (const float*)d_in[0];
    const float* ea  = (const float*)d_in[1];
    const float* u   = (const float*)d_in[2];
    const float* W1a = (const float*)d_in[3];
    // d_in[4] = b1a: cancels in BN1
    const float* g1  = (const float*)d_in[5];
    const float* be1 = (const float*)d_in[6];
    const float* W1b = (const float*)d_in[7];
    const float* b1b = (const float*)d_in[8];
    const float* W2a = (const float*)d_in[9];
    // d_in[10] = b2a: cancels in BN2
    const float* g2  = (const float*)d_in[11];
    const float* be2 = (const float*)d_in[12];
    const float* W2b = (const float*)d_in[13];
    const float* b2b = (const float*)d_in[14];
    const int* ei    = (const int*)d_in[15];
    const int* rowI  = ei;
    const int* colI  = ei + N_EDGES;
    const int* batch = (const int*)d_in[16];
    float* out = (float*)d_out;

    if (ws_size < 260252416ull) return;

    char* ws = (char*)d_ws;
    short* Wp1x   = (short*)(ws + 0);
    short* Wp1e   = (short*)(ws + 32768);
    short* Wp2a   = (short*)(ws + 49152);
    short* Wp2b   = (short*)(ws + 147456);
    float* Wf     = (float*)(ws + 180224);
    float* cb     = (float*)(ws + 245760);
    float* stats1 = (float*)(ws + 246272);
    float* bnp1   = (float*)(ws + 247296);
    float* stats2 = (float*)(ws + 248320);
    float* bnp2   = (float*)(ws + 249344);
    int*   CNTi   = (int*)(ws + 250368);
    int*   OFF    = (int*)(ws + 650368);
    int*   BSUM   = (int*)(ws + 1050368);
    int*   BOFF   = (int*)(ws + 1051392);
    int*   PERM   = (int*)(ws + 1052416);
    short* Aggm   = (short*)(ws + 4252416);
    short* Xap    = (short*)(ws + 29852416ull);
    short* T2     = (short*)(ws + 29852416ull);   // overlays Xap (dead after gemm1n)
    short* T1     = (short*)(ws + 55452416ull);

    hipMemsetAsync(stats1, 0, 4096, stream);      // stats1,bnp1,stats2,bnp2
    hipMemsetAsync(CNTi, 0, 400000, stream);

    // weight prep
    pack_w<<<64, 256, 0, stream>>>(W1a, Wp1x, 128);
    pack_w<<<32, 256, 0, stream>>>(W1a + 128 * 128, Wp1e, 64);
    fold_w<<<64, 256, 0, stream>>>(W1b, W2a, Wf);
    fold_b<<<1, 128, 0, stream>>>(b1b, W2a, cb);
    pack_w<<<64, 256, 0, stream>>>(W2a, Wp2a, 128);                // x block
    pack_w<<<64, 256, 0, stream>>>(Wf, Wp2a + 16384, 128);         // folded middle
    pack_w<<<64, 256, 0, stream>>>(W2a + 256 * 128, Wp2a + 32768, 128);  // u block
    pack_w<<<64, 256, 0, stream>>>(W2b, Wp2b, 128);

    // CSR build
    hist_k<<<(N_EDGES + 255) / 256, 256, 0, stream>>>(colI, CNTi, N_EDGES);
    scan1<<<98, 1024, 0, stream>>>(CNTi, OFF, BSUM, N_NODES);
    scan2<<<1, 128, 0, stream>>>(BSUM, BOFF, 98);
    scan3<<<98, 1024, 0, stream>>>(OFF, BOFF, N_NODES);
    fill_k<<<(N_EDGES + 255) / 256, 256, 0, stream>>>(colI, OFF, PERM, N_EDGES);

    // node-side half of edge layer 1
    gemmX<<<(N_NODES + 127) / 128, 256, 0, stream>>>(x, Wp1x, Xap, N_NODES);

    // edge layer 1 (natural order) + stats
    gemm1n<<<N_EDGES / 128, 256, 0, stream>>>(ea, rowI, Wp1e, Xap, T1, stats1, N_EDGES);
    bn_final<<<1, 128, 0, stream>>>(stats1, g1, be1, bnp1, 1.0f / (float)N_EDGES);

    // segmented selu-mean (edge layer 2 folded into node GEMM)
    segsel<<<1024, 256, 0, stream>>>(T1, bnp1, OFF, CNTi, PERM, Aggm, N_NODES);

    // node MLP
    gemm3_node<<<(N_NODES + 127) / 128, 256, 0, stream>>>(x, Aggm, u, batch, CNTi, cb,
                                                          Wp2a, T2, stats2, N_NODES);
    bn_final<<<1, 128, 0, stream>>>(stats2, g2, be2, bnp2, 1.0f / (float)N_NODES);
    gemm4_node<<<(N_NODES + 127) / 128, 256, 0, stream>>>(T2, bnp2, Wp2b, b2b, out, N_NODES);
}

// Round 5
// 507.059 us; speedup vs baseline: 1.4640x; 1.1197x over previous
//
#include <hip/hip_runtime.h>
#include <hip/hip_bf16.h>
#include <math.h>

// ---------------------------------------------------------------------------
// NodeMLPModel: edge MLP (GEMM+BN+SELU+GEMM) -> scatter-mean -> node MLP.
// Round-5: packed column order p=lr*8+n0 (true col pi(p)=(p&7)*16+(p>>3)) for
// T1/Aggm/T2 -> fully-vectorized epilogue stores; LDS-staged ea; BN folded
// into consumer kernels (no bn_final launches).
// Fragment layout (m89/m91-verified):
//   A: lane holds A[lane&15][8*(lane>>4)+j]
//   B: lane holds B[8*(lane>>4)+j][lane&15]
//   D: lane holds D[4*(lane>>4)+r][lane&15]
// ---------------------------------------------------------------------------

typedef __attribute__((ext_vector_type(8))) short bfrag;
typedef __attribute__((ext_vector_type(4))) float f32x4;

#define N_EDGES 800000
#define N_NODES 100000
#define BN_EPS 1e-5f

static __device__ __forceinline__ short f2bf(float f) {
    union { float f; unsigned u; } v; v.f = f;
    unsigned r = (v.u + 0x7FFFu + ((v.u >> 16) & 1u)) >> 16;  // RNE
    return (short)r;
}
static __device__ __forceinline__ float bf2f(short h) {
    union { unsigned u; float f; } v;
    v.u = ((unsigned)(unsigned short)h) << 16;
    return v.f;
}
static __device__ __forceinline__ unsigned pack2(float lo, float hi) {
    return ((unsigned)(unsigned short)f2bf(lo)) | (((unsigned)(unsigned short)f2bf(hi)) << 16);
}

static __device__ __forceinline__ bfrag load8f_bf(const float* __restrict__ p) {
    float4 a = *(const float4*)p;
    float4 b = *(const float4*)(p + 4);
    bfrag r;
    r[0] = f2bf(a.x); r[1] = f2bf(a.y); r[2] = f2bf(a.z); r[3] = f2bf(a.w);
    r[4] = f2bf(b.x); r[5] = f2bf(b.y); r[6] = f2bf(b.z); r[7] = f2bf(b.w);
    return r;
}

static __device__ __forceinline__ float selu_f(float v) {
    return v > 0.f ? 1.0507009873554805f * v
                   : 1.7580993408473766f * (__expf(v) - 1.0f);
}

// Pack W[K][128] f32 row-major -> bf16 fragment order:
// Wp[(((kb*128 + n)*4 + g)*8 + j)] = W[kb*32 + g*8 + j][n]
__global__ void pack_w(const float* __restrict__ W, short* __restrict__ Wp, int K) {
    int idx = blockIdx.x * 256 + threadIdx.x;
    if (idx >= K * 128) return;
    int k = idx >> 7, n = idx & 127;
    int kb = k >> 5, g = (k >> 3) & 3, j = k & 7;
    Wp[(((size_t)kb * 128 + n) * 4 + g) * 8 + j] = f2bf(W[idx]);
}

// Same but rows taken at true index pi(k) = (k&7)*16 + (k>>3)   (K == 128)
__global__ void pack_w_perm(const float* __restrict__ W, short* __restrict__ Wp) {
    int idx = blockIdx.x * 256 + threadIdx.x;
    if (idx >= 128 * 128) return;
    int k = idx >> 7, n = idx & 127;
    int kt = ((k & 7) << 4) + (k >> 3);
    int kb = k >> 5, g = (k >> 3) & 3, j = k & 7;
    Wp[(((size_t)kb * 128 + n) * 4 + g) * 8 + j] = f2bf(W[(size_t)kt * 128 + n]);
}

// Wf[k][c] = sum_j W1b[k][j] * W2a[128+j][c]
__global__ void fold_w(const float* __restrict__ W1b, const float* __restrict__ W2a,
                       float* __restrict__ Wf) {
    int idx = blockIdx.x * 256 + threadIdx.x;   // 16384
    int k = idx >> 7, c = idx & 127;
    float s = 0.f;
    for (int j = 0; j < 128; ++j) s += W1b[k * 128 + j] * W2a[(size_t)(128 + j) * 128 + c];
    Wf[idx] = s;
}

// cb[c] = sum_j b1b[j] * W2a[128+j][c]
__global__ void fold_b(const float* __restrict__ b1b, const float* __restrict__ W2a,
                       float* __restrict__ cb) {
    int c = threadIdx.x;
    float s = 0.f;
    for (int j = 0; j < 128; ++j) s += b1b[j] * W2a[(size_t)(128 + j) * 128 + c];
    cb[c] = s;
}

// ----------------------------- CSR build -----------------------------------
__global__ void hist_k(const int* __restrict__ col, int* __restrict__ cnt, int E) {
    int i = blockIdx.x * 256 + threadIdx.x;
    if (i < E) atomicAdd(&cnt[col[i]], 1);
}

__global__ void scan1(const int* __restrict__ cnt, int* __restrict__ off,
                      int* __restrict__ bsum, int N) {
    __shared__ int ls[1024];
    int i = blockIdx.x * 1024 + threadIdx.x;
    int v = (i < N) ? cnt[i] : 0;
    ls[threadIdx.x] = v;
    __syncthreads();
    for (int d = 1; d < 1024; d <<= 1) {
        int t = (threadIdx.x >= d) ? ls[threadIdx.x - d] : 0;
        __syncthreads();
        ls[threadIdx.x] += t;
        __syncthreads();
    }
    if (i < N) off[i] = ls[threadIdx.x] - v;
    if (threadIdx.x == 1023) bsum[blockIdx.x] = ls[1023];
}

__global__ void scan2(const int* __restrict__ bsum, int* __restrict__ boff, int NB) {
    __shared__ int ls[128];
    int v = (threadIdx.x < NB) ? bsum[threadIdx.x] : 0;
    ls[threadIdx.x] = v;
    __syncthreads();
    for (int d = 1; d < 128; d <<= 1) {
        int t = (threadIdx.x >= d) ? ls[threadIdx.x - d] : 0;
        __syncthreads();
        ls[threadIdx.x] += t;
        __syncthreads();
    }
    if (threadIdx.x < NB) boff[threadIdx.x] = ls[threadIdx.x] - v;
}

__global__ void scan3(int* __restrict__ off, const int* __restrict__ boff, int N) {
    int i = blockIdx.x * 1024 + threadIdx.x;
    if (i < N) off[i] += boff[blockIdx.x];
}

// Consumes OFF (becomes end offsets: beg = OFF[v]-CNTi[v]).
__global__ void fill_k(const int* __restrict__ col, int* __restrict__ off,
                       int* __restrict__ perm, int E) {
    int e = blockIdx.x * 256 + threadIdx.x;
    if (e < E) {
        int q = atomicAdd(&off[col[e]], 1);
        perm[q] = e;
    }
}

// ---------------------------------------------------------------------------
// gemmX: Xap = packed bf16 of (x @ W1a[:128,:])
// Layout: Xap[v*128 + lr*8 + n0] = Xa[v][n0*16+lr]
__global__ __launch_bounds__(256) void gemmX(
    const float* __restrict__ x, const short* __restrict__ Wp,
    short* __restrict__ Xap, int N)
{
    const int lane = threadIdx.x & 63, wave = threadIdx.x >> 6;
    const int m0 = blockIdx.x * 128 + wave * 32;
    if (m0 >= N) return;  // N % 32 == 0
    const int lr = lane & 15, lg = lane >> 4;
    const int v0 = m0 + lr, v1 = m0 + 16 + lr;

    f32x4 acc[2][8];
#pragma unroll
    for (int t = 0; t < 2; ++t)
#pragma unroll
        for (int n = 0; n < 8; ++n) acc[t][n] = (f32x4){0.f, 0.f, 0.f, 0.f};

#pragma unroll
    for (int kb = 0; kb < 4; ++kb) {
        bfrag a0 = load8f_bf(x + (size_t)v0 * 128 + kb * 32 + lg * 8);
        bfrag a1 = load8f_bf(x + (size_t)v1 * 128 + kb * 32 + lg * 8);
        const short* wb = Wp + (size_t)kb * 4096;
#pragma unroll
        for (int n0 = 0; n0 < 8; ++n0) {
            bfrag b = *(const bfrag*)(wb + ((n0 * 16 + lr) * 4 + lg) * 8);
            acc[0][n0] = __builtin_amdgcn_mfma_f32_16x16x32_bf16(a0, b, acc[0][n0], 0, 0, 0);
            acc[1][n0] = __builtin_amdgcn_mfma_f32_16x16x32_bf16(a1, b, acc[1][n0], 0, 0, 0);
        }
    }
#pragma unroll
    for (int t = 0; t < 2; ++t) {
        const int rbase = m0 + t * 16 + lg * 4;
#pragma unroll
        for (int r = 0; r < 4; ++r) {
            bfrag o;
#pragma unroll
            for (int n0 = 0; n0 < 8; ++n0) o[n0] = f2bf(acc[t][n0][r]);
            *(bfrag*)(Xap + (size_t)(rbase + r) * 128 + lr * 8) = o;
        }
    }
}

// ---------------------------------------------------------------------------
// gemm1n: T1p[e] = packed(ea[e] @ W1a[128:192] + Xa[row[e]])  (natural order)
// LDS-staged ea; fused column sum/sumsq -> stats (true-col indexed)
__global__ __launch_bounds__(256) void gemm1n(
    const float* __restrict__ ea, const int* __restrict__ rowI,
    const short* __restrict__ Wp, const short* __restrict__ Xap,
    short* __restrict__ T1p, float* __restrict__ stats, int E)
{
    const int lane = threadIdx.x & 63, wave = threadIdx.x >> 6;
    const int m0b = blockIdx.x * 128;
    const int m0 = m0b + wave * 32;   // E % 128 == 0
    const int lr = lane & 15, lg = lane >> 4;

    __shared__ __align__(16) unsigned short lds_ea[128 * 72];  // 144B pitch rows
    __shared__ float ls[256];
    ls[threadIdx.x] = 0.f;

    // stage 128 ea rows (64 f32 each) coalesced, convert to bf16
    const float4* eab = (const float4*)ea + (size_t)m0b * 16;
#pragma unroll
    for (int i = 0; i < 8; ++i) {
        int f = threadIdx.x + i * 256;
        int row = f >> 4, col4 = f & 15;
        float4 v = eab[f];
        ushort4 o;
        o.x = (unsigned short)f2bf(v.x); o.y = (unsigned short)f2bf(v.y);
        o.z = (unsigned short)f2bf(v.z); o.w = (unsigned short)f2bf(v.w);
        *(ushort4*)&lds_ea[row * 72 + col4 * 4] = o;
    }
    __syncthreads();

    f32x4 acc[2][8];
#pragma unroll
    for (int t = 0; t < 2; ++t)
#pragma unroll
        for (int n = 0; n < 8; ++n) acc[t][n] = (f32x4){0.f, 0.f, 0.f, 0.f};

    const int lrow = wave * 32 + lr;
#pragma unroll
    for (int kb = 0; kb < 2; ++kb) {
        bfrag a0 = *(const bfrag*)&lds_ea[lrow * 72 + kb * 32 + lg * 8];
        bfrag a1 = *(const bfrag*)&lds_ea[(lrow + 16) * 72 + kb * 32 + lg * 8];
        const short* wb = Wp + (size_t)kb * 4096;
#pragma unroll
        for (int n0 = 0; n0 < 8; ++n0) {
            bfrag b = *(const bfrag*)(wb + ((n0 * 16 + lr) * 4 + lg) * 8);
            acc[0][n0] = __builtin_amdgcn_mfma_f32_16x16x32_bf16(a0, b, acc[0][n0], 0, 0, 0);
            acc[1][n0] = __builtin_amdgcn_mfma_f32_16x16x32_bf16(a1, b, acc[1][n0], 0, 0, 0);
        }
    }
    // epilogue: gather packed Xa rows, add, stats, packed store
    float ps[8], qs[8];
#pragma unroll
    for (int n0 = 0; n0 < 8; ++n0) { ps[n0] = 0.f; qs[n0] = 0.f; }
#pragma unroll
    for (int t = 0; t < 2; ++t) {
        const int rbase = m0 + t * 16 + lg * 4;
        bfrag xa[4];
#pragma unroll
        for (int r = 0; r < 4; ++r)
            xa[r] = *(const bfrag*)(Xap + (size_t)rowI[rbase + r] * 128 + lr * 8);
#pragma unroll
        for (int r = 0; r < 4; ++r) {
            bfrag o;
#pragma unroll
            for (int n0 = 0; n0 < 8; ++n0) {
                float v = acc[t][n0][r] + bf2f(xa[r][n0]);
                ps[n0] += v; qs[n0] += v * v;
                o[n0] = f2bf(v);
            }
            *(bfrag*)(T1p + (size_t)(rbase + r) * 128 + lr * 8) = o;
        }
    }
#pragma unroll
    for (int n0 = 0; n0 < 8; ++n0) {
        const int c = n0 * 16 + lr;
        float p = ps[n0], q = qs[n0];
        p += __shfl_xor(p, 16); p += __shfl_xor(p, 32);
        q += __shfl_xor(q, 16); q += __shfl_xor(q, 32);
        if (lg == 0) { atomicAdd(&ls[c], p); atomicAdd(&ls[128 + c], q); }
    }
    __syncthreads();
    atomicAdd(&stats[threadIdx.x], ls[threadIdx.x]);
}

// ---------------------------------------------------------------------------
// segsel: Aggm[v] (packed) = (1/max(deg,1)) * sum_{e in bucket(v)} selu(BN1(T1p[e]))
// BN params computed per block from stats (permuted to packed positions).
__global__ __launch_bounds__(256) void segsel(
    const short* __restrict__ T1p, const float* __restrict__ stats,
    const float* __restrict__ g1, const float* __restrict__ be1,
    const int* __restrict__ OFF, const int* __restrict__ CNTi,
    const int* __restrict__ perm, short* __restrict__ Aggm, int N, float invR)
{
    __shared__ float ls_sc[128], ls_sh[128];
    if (threadIdx.x < 128) {
        int p = threadIdx.x;
        int c = ((p & 7) << 4) + (p >> 3);       // true col
        float mean = stats[c] * invR;
        float var = stats[128 + c] * invR - mean * mean;
        float sc = g1[c] * rsqrtf(var + BN_EPS);
        ls_sc[p] = sc;
        ls_sh[p] = be1[c] - mean * sc;
    }
    __syncthreads();

    const int lane = threadIdx.x & 63;
    const int wid = blockIdx.x * 4 + (threadIdx.x >> 6);
    const int nw = gridDim.x * 4;
    const float sc0 = ls_sc[2 * lane], sc1 = ls_sc[2 * lane + 1];
    const float sh0 = ls_sh[2 * lane], sh1 = ls_sh[2 * lane + 1];

    for (int v = wid; v < N; v += nw) {
        const int cnt = CNTi[v];
        const int beg = OFF[v] - cnt;   // fill_k advanced OFF to end
        float a0 = 0.f, a1 = 0.f;
        int j = 0;
        for (; j + 4 <= cnt; j += 4) {
            int e0 = perm[beg + j], e1 = perm[beg + j + 1];
            int e2 = perm[beg + j + 2], e3 = perm[beg + j + 3];
            unsigned w0 = *(const unsigned*)(T1p + (size_t)e0 * 128 + lane * 2);
            unsigned w1 = *(const unsigned*)(T1p + (size_t)e1 * 128 + lane * 2);
            unsigned w2 = *(const unsigned*)(T1p + (size_t)e2 * 128 + lane * 2);
            unsigned w3 = *(const unsigned*)(T1p + (size_t)e3 * 128 + lane * 2);
            a0 += selu_f(sc0 * bf2f((short)(w0 & 0xffff)) + sh0);
            a1 += selu_f(sc1 * bf2f((short)(w0 >> 16)) + sh1);
            a0 += selu_f(sc0 * bf2f((short)(w1 & 0xffff)) + sh0);
            a1 += selu_f(sc1 * bf2f((short)(w1 >> 16)) + sh1);
            a0 += selu_f(sc0 * bf2f((short)(w2 & 0xffff)) + sh0);
            a1 += selu_f(sc1 * bf2f((short)(w2 >> 16)) + sh1);
            a0 += selu_f(sc0 * bf2f((short)(w3 & 0xffff)) + sh0);
            a1 += selu_f(sc1 * bf2f((short)(w3 >> 16)) + sh1);
        }
        for (; j < cnt; ++j) {
            int e = perm[beg + j];
            unsigned w = *(const unsigned*)(T1p + (size_t)e * 128 + lane * 2);
            a0 += selu_f(sc0 * bf2f((short)(w & 0xffff)) + sh0);
            a1 += selu_f(sc1 * bf2f((short)(w >> 16)) + sh1);
        }
        const float inv = 1.0f / fmaxf((float)cnt, 1.0f);
        *(unsigned*)(Aggm + (size_t)v * 128 + lane * 2) = pack2(a0 * inv, a1 * inv);
    }
}

// ---------------------------------------------------------------------------
// gemm3: T2p = packed([x, Aggm(packed), u[batch]] @ W2a' + (deg>0)*cb) ; fused stats
// (middle-block weights pre-permuted to match Aggm's packed K order)
__global__ __launch_bounds__(256) void gemm3_node(
    const float* __restrict__ x, const short* __restrict__ Aggm,
    const float* __restrict__ u, const int* __restrict__ batch,
    const int* __restrict__ CNTi, const float* __restrict__ cb,
    const short* __restrict__ Wp, short* __restrict__ T2p,
    float* __restrict__ stats, int N)
{
    const int lane = threadIdx.x & 63, wave = threadIdx.x >> 6;
    const int m0 = blockIdx.x * 128 + wave * 32;
    const bool active = (m0 < N);   // N % 32 == 0
    const int lr = lane & 15, lg = lane >> 4;
    __shared__ float ls[256];
    ls[threadIdx.x] = 0.f;
    __syncthreads();

    const int v0 = active ? m0 + lr : 0, v1 = active ? m0 + 16 + lr : 0;
    const float* u0 = u + (size_t)batch[v0] * 128;
    const float* u1 = u + (size_t)batch[v1] * 128;

    f32x4 acc[2][8];
#pragma unroll
    for (int t = 0; t < 2; ++t)
#pragma unroll
        for (int n = 0; n < 8; ++n) acc[t][n] = (f32x4){0.f, 0.f, 0.f, 0.f};

    if (active) {
#pragma unroll
        for (int kb = 0; kb < 12; ++kb) {
            bfrag a0, a1;
            if (kb >= 4 && kb < 8) {
                a0 = *(const bfrag*)(Aggm + (size_t)v0 * 128 + (kb - 4) * 32 + lg * 8);
                a1 = *(const bfrag*)(Aggm + (size_t)v1 * 128 + (kb - 4) * 32 + lg * 8);
            } else {
                const float *p0, *p1;
                if (kb < 4) {
                    p0 = x + (size_t)v0 * 128 + kb * 32 + lg * 8;
                    p1 = x + (size_t)v1 * 128 + kb * 32 + lg * 8;
                } else {
                    p0 = u0 + (kb - 8) * 32 + lg * 8;
                    p1 = u1 + (kb - 8) * 32 + lg * 8;
                }
                a0 = load8f_bf(p0);
                a1 = load8f_bf(p1);
            }
            const short* wb = Wp + (size_t)kb * 4096;
#pragma unroll
            for (int n0 = 0; n0 < 8; ++n0) {
                bfrag b = *(const bfrag*)(wb + ((n0 * 16 + lr) * 4 + lg) * 8);
                acc[0][n0] = __builtin_amdgcn_mfma_f32_16x16x32_bf16(a0, b, acc[0][n0], 0, 0, 0);
                acc[1][n0] = __builtin_amdgcn_mfma_f32_16x16x32_bf16(a1, b, acc[1][n0], 0, 0, 0);
            }
        }
        // epilogue: + flag*cb, stats, packed store
        float cbl[8];
#pragma unroll
        for (int n0 = 0; n0 < 8; ++n0) cbl[n0] = cb[n0 * 16 + lr];
        float ps[8], qs[8];
#pragma unroll
        for (int n0 = 0; n0 < 8; ++n0) { ps[n0] = 0.f; qs[n0] = 0.f; }
#pragma unroll
        for (int t = 0; t < 2; ++t) {
            const int rbase = m0 + t * 16 + lg * 4;
            float fl[4];
#pragma unroll
            for (int r = 0; r < 4; ++r) fl[r] = (CNTi[rbase + r] > 0) ? 1.f : 0.f;
#pragma unroll
            for (int r = 0; r < 4; ++r) {
                bfrag o;
#pragma unroll
                for (int n0 = 0; n0 < 8; ++n0) {
                    float v = acc[t][n0][r] + fl[r] * cbl[n0];
                    ps[n0] += v; qs[n0] += v * v;
                    o[n0] = f2bf(v);
                }
                *(bfrag*)(T2p + (size_t)(rbase + r) * 128 + lr * 8) = o;
            }
        }
#pragma unroll
        for (int n0 = 0; n0 < 8; ++n0) {
            const int c = n0 * 16 + lr;
            float p = ps[n0], q = qs[n0];
            p += __shfl_xor(p, 16); p += __shfl_xor(p, 32);
            q += __shfl_xor(q, 16); q += __shfl_xor(q, 32);
            if (lg == 0) { atomicAdd(&ls[c], p); atomicAdd(&ls[128 + c], q); }
        }
    }
    __syncthreads();
    atomicAdd(&stats[threadIdx.x], ls[threadIdx.x]);
}

// Node GEMM2: out = selu(BN2(T2p)) @ W2b' + b2b   (f32 true-order output)
// W2b' rows pre-permuted to packed K order; BN params from stats in block prologue.
__global__ __launch_bounds__(256) void gemm4_node(
    const short* __restrict__ T2p, const float* __restrict__ stats,
    const float* __restrict__ g2, const float* __restrict__ be2,
    const short* __restrict__ Wp, const float* __restrict__ b2b,
    float* __restrict__ out, int N, float invR)
{
    __shared__ float ls_sc[128], ls_sh[128];
    if (threadIdx.x < 128) {
        int c = threadIdx.x;                     // true col
        float mean = stats[c] * invR;
        float var = stats[128 + c] * invR - mean * mean;
        float sc = g2[c] * rsqrtf(var + BN_EPS);
        ls_sc[c] = sc;
        ls_sh[c] = be2[c] - mean * sc;
    }
    __syncthreads();

    const int lane = threadIdx.x & 63, wave = threadIdx.x >> 6;
    const int m0 = blockIdx.x * 128 + wave * 32;
    if (m0 >= N) return;   // N % 32 == 0
    const int lr = lane & 15, lg = lane >> 4;
    const int e0 = m0 + lr, e1 = m0 + 16 + lr;

    f32x4 acc[2][8];
#pragma unroll
    for (int n0 = 0; n0 < 8; ++n0) {
        float bias = b2b[n0 * 16 + lr];
        acc[0][n0] = (f32x4){bias, bias, bias, bias};
        acc[1][n0] = (f32x4){bias, bias, bias, bias};
    }
#pragma unroll
    for (int kb = 0; kb < 4; ++kb) {
        // packed pos p = kb*32+lg*8+j  ->  true col j*16 + kb*4 + lg
        float scl[8], shf[8];
#pragma unroll
        for (int j = 0; j < 8; ++j) {
            int c = j * 16 + kb * 4 + lg;
            scl[j] = ls_sc[c];
            shf[j] = ls_sh[c];
        }
        bfrag r0 = *(const bfrag*)(T2p + (size_t)e0 * 128 + kb * 32 + lg * 8);
        bfrag r1 = *(const bfrag*)(T2p + (size_t)e1 * 128 + kb * 32 + lg * 8);
        bfrag a0, a1;
#pragma unroll
        for (int j = 0; j < 8; ++j) {
            a0[j] = f2bf(selu_f(bf2f(r0[j]) * scl[j] + shf[j]));
            a1[j] = f2bf(selu_f(bf2f(r1[j]) * scl[j] + shf[j]));
        }
        const short* wb = Wp + (size_t)kb * 4096;
#pragma unroll
        for (int n0 = 0; n0 < 8; ++n0) {
            bfrag b = *(const bfrag*)(wb + ((n0 * 16 + lr) * 4 + lg) * 8);
            acc[0][n0] = __builtin_amdgcn_mfma_f32_16x16x32_bf16(a0, b, acc[0][n0], 0, 0, 0);
            acc[1][n0] = __builtin_amdgcn_mfma_f32_16x16x32_bf16(a1, b, acc[1][n0], 0, 0, 0);
        }
    }
#pragma unroll
    for (int t = 0; t < 2; ++t) {
        const int rbase = m0 + t * 16 + lg * 4;
#pragma unroll
        for (int n0 = 0; n0 < 8; ++n0) {
            const int c = n0 * 16 + lr;
#pragma unroll
            for (int r = 0; r < 4; ++r)
                out[(size_t)(rbase + r) * 128 + c] = acc[t][n0][r];
        }
    }
}

// ---------------------------------------------------------------------------
// Workspace layout (bytes):
//   0        Wp1x 32768  | 32768 Wp1e 16384 | 49152 Wp2a 98304 | 147456 Wp2b 32768
//   180224   Wf 65536    | 245760 cb 512
//   246272   stats1 1024 | 247296 stats2 1024
//   250368   CNTi 400000 | 650368 OFF 400000
//   1050368  BSUM 1024   | 1051392 BOFF 1024
//   1052416  PERM 3200000
//   4252416  Aggm bf16 100000x128 (25600000)
//   29852416 Xap bf16 100000x128 (25600000)  [phase2: T2p overlays]
//   55452416 T1p bf16 800000x128 (204800000)
//   total: 260252416
// ---------------------------------------------------------------------------
extern "C" void kernel_launch(void* const* d_in, const int* in_sizes, int n_in,
                              void* d_out, int out_size, void* d_ws, size_t ws_size,
                              hipStream_t stream)
{
    const float* x   = (const float*)d_in[0];
    const float* ea  = (const float*)d_in[1];
    const float* u   = (const float*)d_in[2];
    const float* W1a = (const float*)d_in[3];
    // d_in[4] = b1a: cancels in BN1
    const float* g1  = (const float*)d_in[5];
    const float* be1 = (const float*)d_in[6];
    const float* W1b = (const float*)d_in[7];
    const float* b1b = (const float*)d_in[8];
    const float* W2a = (const float*)d_in[9];
    // d_in[10] = b2a: cancels in BN2
    const float* g2  = (const float*)d_in[11];
    const float* be2 = (const float*)d_in[12];
    const float* W2b = (const float*)d_in[13];
    const float* b2b = (const float*)d_in[14];
    const int* ei    = (const int*)d_in[15];
    const int* rowI  = ei;
    const int* colI  = ei + N_EDGES;
    const int* batch = (const int*)d_in[16];
    float* out = (float*)d_out;

    if (ws_size < 260252416ull) return;

    char* ws = (char*)d_ws;
    short* Wp1x   = (short*)(ws + 0);
    short* Wp1e   = (short*)(ws + 32768);
    short* Wp2a   = (short*)(ws + 49152);
    short* Wp2b   = (short*)(ws + 147456);
    float* Wf     = (float*)(ws + 180224);
    float* cb     = (float*)(ws + 245760);
    float* stats1 = (float*)(ws + 246272);
    float* stats2 = (float*)(ws + 247296);
    int*   CNTi   = (int*)(ws + 250368);
    int*   OFF    = (int*)(ws + 650368);
    int*   BSUM   = (int*)(ws + 1050368);
    int*   BOFF   = (int*)(ws + 1051392);
    int*   PERM   = (int*)(ws + 1052416);
    short* Aggm   = (short*)(ws + 4252416);
    short* Xap    = (short*)(ws + 29852416ull);
    short* T2p    = (short*)(ws + 29852416ull);   // overlays Xap (dead after gemm1n)
    short* T1p    = (short*)(ws + 55452416ull);

    hipMemsetAsync(stats1, 0, 2048, stream);      // stats1, stats2
    hipMemsetAsync(CNTi, 0, 400000, stream);

    // weight prep
    pack_w<<<64, 256, 0, stream>>>(W1a, Wp1x, 128);
    pack_w<<<32, 256, 0, stream>>>(W1a + 128 * 128, Wp1e, 64);
    fold_w<<<64, 256, 0, stream>>>(W1b, W2a, Wf);
    fold_b<<<1, 128, 0, stream>>>(b1b, W2a, cb);
    pack_w<<<64, 256, 0, stream>>>(W2a, Wp2a, 128);                  // x block
    pack_w_perm<<<64, 256, 0, stream>>>(Wf, Wp2a + 16384);           // folded middle (perm)
    pack_w<<<64, 256, 0, stream>>>(W2a + 256 * 128, Wp2a + 32768, 128);  // u block
    pack_w_perm<<<64, 256, 0, stream>>>(W2b, Wp2b);                  // perm for packed T2

    // CSR build
    hist_k<<<(N_EDGES + 255) / 256, 256, 0, stream>>>(colI, CNTi, N_EDGES);
    scan1<<<98, 1024, 0, stream>>>(CNTi, OFF, BSUM, N_NODES);
    scan2<<<1, 128, 0, stream>>>(BSUM, BOFF, 98);
    scan3<<<98, 1024, 0, stream>>>(OFF, BOFF, N_NODES);
    fill_k<<<(N_EDGES + 255) / 256, 256, 0, stream>>>(colI, OFF, PERM, N_EDGES);

    // node-side half of edge layer 1
    gemmX<<<(N_NODES + 127) / 128, 256, 0, stream>>>(x, Wp1x, Xap, N_NODES);

    // edge layer 1 (natural order) + stats
    gemm1n<<<N_EDGES / 128, 256, 0, stream>>>(ea, rowI, Wp1e, Xap, T1p, stats1, N_EDGES);

    // segmented selu-mean (edge layer 2 folded into node GEMM); BN1 inline
    segsel<<<2048, 256, 0, stream>>>(T1p, stats1, g1, be1, OFF, CNTi, PERM, Aggm,
                                     N_NODES, 1.0f / (float)N_EDGES);

    // node MLP
    gemm3_node<<<(N_NODES + 127) / 128, 256, 0, stream>>>(x, Aggm, u, batch, CNTi, cb,
                                                          Wp2a, T2p, stats2, N_NODES);
    gemm4_node<<<(N_NODES + 127) / 128, 256, 0, stream>>>(T2p, stats2, g2, be2, Wp2b, b2b,
                                                          out, N_NODES, 1.0f / (float)N_NODES);
}

// Round 6
// 467.042 us; speedup vs baseline: 1.5894x; 1.0857x over previous
//
#include <hip/hip_runtime.h>
#include <hip/hip_bf16.h>
#include <math.h>

// ---------------------------------------------------------------------------
// NodeMLPModel: edge MLP (GEMM+BN+SELU+GEMM) -> scatter-mean -> node MLP.
// Round-6: gemm1n hoists Xap gathers ahead of MFMA (latency hidden) and
// writes T1p at CSR-sorted positions (SPOS = inverse perm) so segsel reads
// T1p fully sequentially (no perm indirection). segsel: half-wave per row,
// contiguous node chunks. Packed column order p=lr*8+n0 (true col
// pi(p)=(p&7)*16+(p>>3)) retained for T1p/Aggm/T2p.
// Fragment layout (m89/m91-verified):
//   A: lane holds A[lane&15][8*(lane>>4)+j]
//   B: lane holds B[8*(lane>>4)+j][lane&15]
//   D: lane holds D[4*(lane>>4)+r][lane&15]
// ---------------------------------------------------------------------------

typedef __attribute__((ext_vector_type(8))) short bfrag;
typedef __attribute__((ext_vector_type(4))) float f32x4;

#define N_EDGES 800000
#define N_NODES 100000
#define BN_EPS 1e-5f

static __device__ __forceinline__ short f2bf(float f) {
    union { float f; unsigned u; } v; v.f = f;
    unsigned r = (v.u + 0x7FFFu + ((v.u >> 16) & 1u)) >> 16;  // RNE
    return (short)r;
}
static __device__ __forceinline__ float bf2f(short h) {
    union { unsigned u; float f; } v;
    v.u = ((unsigned)(unsigned short)h) << 16;
    return v.f;
}
static __device__ __forceinline__ unsigned pack2(float lo, float hi) {
    return ((unsigned)(unsigned short)f2bf(lo)) | (((unsigned)(unsigned short)f2bf(hi)) << 16);
}

static __device__ __forceinline__ bfrag load8f_bf(const float* __restrict__ p) {
    float4 a = *(const float4*)p;
    float4 b = *(const float4*)(p + 4);
    bfrag r;
    r[0] = f2bf(a.x); r[1] = f2bf(a.y); r[2] = f2bf(a.z); r[3] = f2bf(a.w);
    r[4] = f2bf(b.x); r[5] = f2bf(b.y); r[6] = f2bf(b.z); r[7] = f2bf(b.w);
    return r;
}

static __device__ __forceinline__ float selu_f(float v) {
    return v > 0.f ? 1.0507009873554805f * v
                   : 1.7580993408473766f * (__expf(v) - 1.0f);
}

// Pack W[K][128] f32 row-major -> bf16 fragment order:
// Wp[(((kb*128 + n)*4 + g)*8 + j)] = W[kb*32 + g*8 + j][n]
__global__ void pack_w(const float* __restrict__ W, short* __restrict__ Wp, int K) {
    int idx = blockIdx.x * 256 + threadIdx.x;
    if (idx >= K * 128) return;
    int k = idx >> 7, n = idx & 127;
    int kb = k >> 5, g = (k >> 3) & 3, j = k & 7;
    Wp[(((size_t)kb * 128 + n) * 4 + g) * 8 + j] = f2bf(W[idx]);
}

// Same but rows taken at true index pi(k) = (k&7)*16 + (k>>3)   (K == 128)
__global__ void pack_w_perm(const float* __restrict__ W, short* __restrict__ Wp) {
    int idx = blockIdx.x * 256 + threadIdx.x;
    if (idx >= 128 * 128) return;
    int k = idx >> 7, n = idx & 127;
    int kt = ((k & 7) << 4) + (k >> 3);
    int kb = k >> 5, g = (k >> 3) & 3, j = k & 7;
    Wp[(((size_t)kb * 128 + n) * 4 + g) * 8 + j] = f2bf(W[(size_t)kt * 128 + n]);
}

// Wf[k][c] = sum_j W1b[k][j] * W2a[128+j][c]
__global__ void fold_w(const float* __restrict__ W1b, const float* __restrict__ W2a,
                       float* __restrict__ Wf) {
    int idx = blockIdx.x * 256 + threadIdx.x;   // 16384
    int k = idx >> 7, c = idx & 127;
    float s = 0.f;
    for (int j = 0; j < 128; ++j) s += W1b[k * 128 + j] * W2a[(size_t)(128 + j) * 128 + c];
    Wf[idx] = s;
}

// cb[c] = sum_j b1b[j] * W2a[128+j][c]
__global__ void fold_b(const float* __restrict__ b1b, const float* __restrict__ W2a,
                       float* __restrict__ cb) {
    int c = threadIdx.x;
    float s = 0.f;
    for (int j = 0; j < 128; ++j) s += b1b[j] * W2a[(size_t)(128 + j) * 128 + c];
    cb[c] = s;
}

// ----------------------------- CSR build -----------------------------------
__global__ void hist_k(const int* __restrict__ col, int* __restrict__ cnt, int E) {
    int i = blockIdx.x * 256 + threadIdx.x;
    if (i < E) atomicAdd(&cnt[col[i]], 1);
}

__global__ void scan1(const int* __restrict__ cnt, int* __restrict__ off,
                      int* __restrict__ bsum, int N) {
    __shared__ int ls[1024];
    int i = blockIdx.x * 1024 + threadIdx.x;
    int v = (i < N) ? cnt[i] : 0;
    ls[threadIdx.x] = v;
    __syncthreads();
    for (int d = 1; d < 1024; d <<= 1) {
        int t = (threadIdx.x >= d) ? ls[threadIdx.x - d] : 0;
        __syncthreads();
        ls[threadIdx.x] += t;
        __syncthreads();
    }
    if (i < N) off[i] = ls[threadIdx.x] - v;
    if (threadIdx.x == 1023) bsum[blockIdx.x] = ls[1023];
}

__global__ void scan2(const int* __restrict__ bsum, int* __restrict__ boff, int NB) {
    __shared__ int ls[128];
    int v = (threadIdx.x < NB) ? bsum[threadIdx.x] : 0;
    ls[threadIdx.x] = v;
    __syncthreads();
    for (int d = 1; d < 128; d <<= 1) {
        int t = (threadIdx.x >= d) ? ls[threadIdx.x - d] : 0;
        __syncthreads();
        ls[threadIdx.x] += t;
        __syncthreads();
    }
    if (threadIdx.x < NB) boff[threadIdx.x] = ls[threadIdx.x] - v;
}

__global__ void scan3(int* __restrict__ off, const int* __restrict__ boff, int N) {
    int i = blockIdx.x * 1024 + threadIdx.x;
    if (i < N) off[i] += boff[blockIdx.x];
}

// Consumes OFF (becomes end offsets: beg = OFF[v]-CNTi[v]).
// SPOS[e] = sorted position of edge e (inverse permutation).
__global__ void fill_k(const int* __restrict__ col, int* __restrict__ off,
                       int* __restrict__ spos, int E) {
    int e = blockIdx.x * 256 + threadIdx.x;
    if (e < E) spos[e] = atomicAdd(&off[col[e]], 1);
}

// ---------------------------------------------------------------------------
// gemmX: Xap = packed bf16 of (x @ W1a[:128,:])
// Layout: Xap[v*128 + lr*8 + n0] = Xa[v][n0*16+lr]
__global__ __launch_bounds__(256) void gemmX(
    const float* __restrict__ x, const short* __restrict__ Wp,
    short* __restrict__ Xap, int N)
{
    const int lane = threadIdx.x & 63, wave = threadIdx.x >> 6;
    const int m0 = blockIdx.x * 128 + wave * 32;
    if (m0 >= N) return;  // N % 32 == 0
    const int lr = lane & 15, lg = lane >> 4;
    const int v0 = m0 + lr, v1 = m0 + 16 + lr;

    f32x4 acc[2][8];
#pragma unroll
    for (int t = 0; t < 2; ++t)
#pragma unroll
        for (int n = 0; n < 8; ++n) acc[t][n] = (f32x4){0.f, 0.f, 0.f, 0.f};

#pragma unroll
    for (int kb = 0; kb < 4; ++kb) {
        bfrag a0 = load8f_bf(x + (size_t)v0 * 128 + kb * 32 + lg * 8);
        bfrag a1 = load8f_bf(x + (size_t)v1 * 128 + kb * 32 + lg * 8);
        const short* wb = Wp + (size_t)kb * 4096;
#pragma unroll
        for (int n0 = 0; n0 < 8; ++n0) {
            bfrag b = *(const bfrag*)(wb + ((n0 * 16 + lr) * 4 + lg) * 8);
            acc[0][n0] = __builtin_amdgcn_mfma_f32_16x16x32_bf16(a0, b, acc[0][n0], 0, 0, 0);
            acc[1][n0] = __builtin_amdgcn_mfma_f32_16x16x32_bf16(a1, b, acc[1][n0], 0, 0, 0);
        }
    }
#pragma unroll
    for (int t = 0; t < 2; ++t) {
        const int rbase = m0 + t * 16 + lg * 4;
#pragma unroll
        for (int r = 0; r < 4; ++r) {
            bfrag o;
#pragma unroll
            for (int n0 = 0; n0 < 8; ++n0) o[n0] = f2bf(acc[t][n0][r]);
            *(bfrag*)(Xap + (size_t)(rbase + r) * 128 + lr * 8) = o;
        }
    }
}

// ---------------------------------------------------------------------------
// gemm1n: T1p[SPOS[e]] = packed(ea[e] @ W1a[128:192] + Xa[row[e]])
// (natural-order processing; scatter store to CSR-sorted positions)
// Xap gathers hoisted ahead of MFMA so their latency hides under ea+MFMA.
// Fused column sum/sumsq -> stats (true-col indexed).
__global__ __launch_bounds__(256) void gemm1n(
    const float* __restrict__ ea, const int* __restrict__ rowI,
    const int* __restrict__ SPOS, const short* __restrict__ Wp,
    const short* __restrict__ Xap, short* __restrict__ T1p,
    float* __restrict__ stats, int E)
{
    const int lane = threadIdx.x & 63, wave = threadIdx.x >> 6;
    const int m0 = blockIdx.x * 128 + wave * 32;   // E % 128 == 0
    const int lr = lane & 15, lg = lane >> 4;
    __shared__ float ls[256];
    ls[threadIdx.x] = 0.f;
    __syncthreads();

    // --- hoisted: indices + Xa gathers (latency hidden under ea loads+MFMA)
    int spos[2][4];
    bfrag xa[2][4];
#pragma unroll
    for (int t = 0; t < 2; ++t) {
        const int rbase = m0 + t * 16 + lg * 4;
#pragma unroll
        for (int r = 0; r < 4; ++r) {
            const int e = rbase + r;
            spos[t][r] = SPOS[e];
            xa[t][r] = *(const bfrag*)(Xap + (size_t)rowI[e] * 128 + lr * 8);
        }
    }

    const float* er0 = ea + (size_t)(m0 + lr) * 64;
    const float* er1 = ea + (size_t)(m0 + 16 + lr) * 64;

    f32x4 acc[2][8];
#pragma unroll
    for (int t = 0; t < 2; ++t)
#pragma unroll
        for (int n = 0; n < 8; ++n) acc[t][n] = (f32x4){0.f, 0.f, 0.f, 0.f};

#pragma unroll
    for (int kb = 0; kb < 2; ++kb) {
        bfrag a0 = load8f_bf(er0 + kb * 32 + lg * 8);
        bfrag a1 = load8f_bf(er1 + kb * 32 + lg * 8);
        const short* wb = Wp + (size_t)kb * 4096;
#pragma unroll
        for (int n0 = 0; n0 < 8; ++n0) {
            bfrag b = *(const bfrag*)(wb + ((n0 * 16 + lr) * 4 + lg) * 8);
            acc[0][n0] = __builtin_amdgcn_mfma_f32_16x16x32_bf16(a0, b, acc[0][n0], 0, 0, 0);
            acc[1][n0] = __builtin_amdgcn_mfma_f32_16x16x32_bf16(a1, b, acc[1][n0], 0, 0, 0);
        }
    }

    // epilogue: add gathered Xa, stats, scatter-store packed rows (256B segs)
    float ps[8], qs[8];
#pragma unroll
    for (int n0 = 0; n0 < 8; ++n0) { ps[n0] = 0.f; qs[n0] = 0.f; }
#pragma unroll
    for (int t = 0; t < 2; ++t) {
#pragma unroll
        for (int r = 0; r < 4; ++r) {
            bfrag o;
#pragma unroll
            for (int n0 = 0; n0 < 8; ++n0) {
                float v = acc[t][n0][r] + bf2f(xa[t][r][n0]);
                ps[n0] += v; qs[n0] += v * v;
                o[n0] = f2bf(v);
            }
            *(bfrag*)(T1p + (size_t)spos[t][r] * 128 + lr * 8) = o;
        }
    }
#pragma unroll
    for (int n0 = 0; n0 < 8; ++n0) {
        const int c = n0 * 16 + lr;
        float p = ps[n0], q = qs[n0];
        p += __shfl_xor(p, 16); p += __shfl_xor(p, 32);
        q += __shfl_xor(q, 16); q += __shfl_xor(q, 32);
        if (lg == 0) { atomicAdd(&ls[c], p); atomicAdd(&ls[128 + c], q); }
    }
    __syncthreads();
    atomicAdd(&stats[threadIdx.x], ls[threadIdx.x]);
}

// ---------------------------------------------------------------------------
// segsel: Aggm[v] (packed) = (1/max(deg,1)) * sum_{rows in bucket(v)} selu(BN1(T1p))
// T1p is bucket-contiguous -> pure sequential reads. Half-wave per row
// (h = lane>>5), lane covers packed cols t*4..t*4+3 (uint2 = 8B).
// Contiguous node chunks per wave for L2 locality. BN params from stats.
__global__ __launch_bounds__(256) void segsel(
    const short* __restrict__ T1p, const float* __restrict__ stats,
    const float* __restrict__ g1, const float* __restrict__ be1,
    const int* __restrict__ OFF, const int* __restrict__ CNTi,
    short* __restrict__ Aggm, int N, float invR)
{
    __shared__ float ls_sc[128], ls_sh[128];
    if (threadIdx.x < 128) {
        int p = threadIdx.x;
        int c = ((p & 7) << 4) + (p >> 3);       // true col
        float mean = stats[c] * invR;
        float var = stats[128 + c] * invR - mean * mean;
        float sc = g1[c] * rsqrtf(var + BN_EPS);
        ls_sc[p] = sc;
        ls_sh[p] = be1[c] - mean * sc;
    }
    __syncthreads();

    const int lane = threadIdx.x & 63;
    const int h = lane >> 5, t = lane & 31;
    const int wid = blockIdx.x * 4 + (threadIdx.x >> 6);
    const int nw = gridDim.x * 4;
    const int chunk = (N + nw - 1) / nw;
    const int v0 = wid * chunk;
    const int v1 = (v0 + chunk < N) ? v0 + chunk : N;

    const float sc0 = ls_sc[t * 4 + 0], sc1 = ls_sc[t * 4 + 1];
    const float sc2 = ls_sc[t * 4 + 2], sc3 = ls_sc[t * 4 + 3];
    const float sh0 = ls_sh[t * 4 + 0], sh1 = ls_sh[t * 4 + 1];
    const float sh2 = ls_sh[t * 4 + 2], sh3 = ls_sh[t * 4 + 3];

    for (int v = v0; v < v1; ++v) {
        const int cnt = CNTi[v];
        const int beg = OFF[v] - cnt;   // fill_k advanced OFF to end
        const short* base = T1p + (size_t)beg * 128 + t * 4;
        float a0 = 0.f, a1 = 0.f, a2 = 0.f, a3 = 0.f;
        int j = 0;
        for (; j + 4 <= cnt; j += 4) {
            uint2 wA = *(const uint2*)(base + (size_t)(j + h) * 128);
            uint2 wB = *(const uint2*)(base + (size_t)(j + 2 + h) * 128);
            a0 += selu_f(sc0 * bf2f((short)(wA.x & 0xffff)) + sh0);
            a1 += selu_f(sc1 * bf2f((short)(wA.x >> 16)) + sh1);
            a2 += selu_f(sc2 * bf2f((short)(wA.y & 0xffff)) + sh2);
            a3 += selu_f(sc3 * bf2f((short)(wA.y >> 16)) + sh3);
            a0 += selu_f(sc0 * bf2f((short)(wB.x & 0xffff)) + sh0);
            a1 += selu_f(sc1 * bf2f((short)(wB.x >> 16)) + sh1);
            a2 += selu_f(sc2 * bf2f((short)(wB.y & 0xffff)) + sh2);
            a3 += selu_f(sc3 * bf2f((short)(wB.y >> 16)) + sh3);
        }
        for (; j < cnt; j += 2) {
            if (j + h < cnt) {
                uint2 w = *(const uint2*)(base + (size_t)(j + h) * 128);
                a0 += selu_f(sc0 * bf2f((short)(w.x & 0xffff)) + sh0);
                a1 += selu_f(sc1 * bf2f((short)(w.x >> 16)) + sh1);
                a2 += selu_f(sc2 * bf2f((short)(w.y & 0xffff)) + sh2);
                a3 += selu_f(sc3 * bf2f((short)(w.y >> 16)) + sh3);
            }
        }
        a0 += __shfl_xor(a0, 32); a1 += __shfl_xor(a1, 32);
        a2 += __shfl_xor(a2, 32); a3 += __shfl_xor(a3, 32);
        if (h == 0) {
            const float inv = 1.0f / fmaxf((float)cnt, 1.0f);
            uint2 o;
            o.x = pack2(a0 * inv, a1 * inv);
            o.y = pack2(a2 * inv, a3 * inv);
            *(uint2*)(Aggm + (size_t)v * 128 + t * 4) = o;
        }
    }
}

// ---------------------------------------------------------------------------
// gemm3: T2p = packed([x, Aggm(packed), u[batch]] @ W2a' + (deg>0)*cb) ; fused stats
// (middle-block weights pre-permuted to match Aggm's packed K order)
__global__ __launch_bounds__(256) void gemm3_node(
    const float* __restrict__ x, const short* __restrict__ Aggm,
    const float* __restrict__ u, const int* __restrict__ batch,
    const int* __restrict__ CNTi, const float* __restrict__ cb,
    const short* __restrict__ Wp, short* __restrict__ T2p,
    float* __restrict__ stats, int N)
{
    const int lane = threadIdx.x & 63, wave = threadIdx.x >> 6;
    const int m0 = blockIdx.x * 128 + wave * 32;
    const bool active = (m0 < N);   // N % 32 == 0
    const int lr = lane & 15, lg = lane >> 4;
    __shared__ float ls[256];
    ls[threadIdx.x] = 0.f;
    __syncthreads();

    const int v0 = active ? m0 + lr : 0, v1 = active ? m0 + 16 + lr : 0;
    const float* u0 = u + (size_t)batch[v0] * 128;
    const float* u1 = u + (size_t)batch[v1] * 128;

    f32x4 acc[2][8];
#pragma unroll
    for (int t = 0; t < 2; ++t)
#pragma unroll
        for (int n = 0; n < 8; ++n) acc[t][n] = (f32x4){0.f, 0.f, 0.f, 0.f};

    if (active) {
#pragma unroll
        for (int kb = 0; kb < 12; ++kb) {
            bfrag a0, a1;
            if (kb >= 4 && kb < 8) {
                a0 = *(const bfrag*)(Aggm + (size_t)v0 * 128 + (kb - 4) * 32 + lg * 8);
                a1 = *(const bfrag*)(Aggm + (size_t)v1 * 128 + (kb - 4) * 32 + lg * 8);
            } else {
                const float *p0, *p1;
                if (kb < 4) {
                    p0 = x + (size_t)v0 * 128 + kb * 32 + lg * 8;
                    p1 = x + (size_t)v1 * 128 + kb * 32 + lg * 8;
                } else {
                    p0 = u0 + (kb - 8) * 32 + lg * 8;
                    p1 = u1 + (kb - 8) * 32 + lg * 8;
                }
                a0 = load8f_bf(p0);
                a1 = load8f_bf(p1);
            }
            const short* wb = Wp + (size_t)kb * 4096;
#pragma unroll
            for (int n0 = 0; n0 < 8; ++n0) {
                bfrag b = *(const bfrag*)(wb + ((n0 * 16 + lr) * 4 + lg) * 8);
                acc[0][n0] = __builtin_amdgcn_mfma_f32_16x16x32_bf16(a0, b, acc[0][n0], 0, 0, 0);
                acc[1][n0] = __builtin_amdgcn_mfma_f32_16x16x32_bf16(a1, b, acc[1][n0], 0, 0, 0);
            }
        }
        // epilogue: + flag*cb, stats, packed store
        float cbl[8];
#pragma unroll
        for (int n0 = 0; n0 < 8; ++n0) cbl[n0] = cb[n0 * 16 + lr];
        float ps[8], qs[8];
#pragma unroll
        for (int n0 = 0; n0 < 8; ++n0) { ps[n0] = 0.f; qs[n0] = 0.f; }
#pragma unroll
        for (int t = 0; t < 2; ++t) {
            const int rbase = m0 + t * 16 + lg * 4;
            float fl[4];
#pragma unroll
            for (int r = 0; r < 4; ++r) fl[r] = (CNTi[rbase + r] > 0) ? 1.f : 0.f;
#pragma unroll
            for (int r = 0; r < 4; ++r) {
                bfrag o;
#pragma unroll
                for (int n0 = 0; n0 < 8; ++n0) {
                    float v = acc[t][n0][r] + fl[r] * cbl[n0];
                    ps[n0] += v; qs[n0] += v * v;
                    o[n0] = f2bf(v);
                }
                *(bfrag*)(T2p + (size_t)(rbase + r) * 128 + lr * 8) = o;
            }
        }
#pragma unroll
        for (int n0 = 0; n0 < 8; ++n0) {
            const int c = n0 * 16 + lr;
            float p = ps[n0], q = qs[n0];
            p += __shfl_xor(p, 16); p += __shfl_xor(p, 32);
            q += __shfl_xor(q, 16); q += __shfl_xor(q, 32);
            if (lg == 0) { atomicAdd(&ls[c], p); atomicAdd(&ls[128 + c], q); }
        }
    }
    __syncthreads();
    atomicAdd(&stats[threadIdx.x], ls[threadIdx.x]);
}

// Node GEMM2: out = selu(BN2(T2p)) @ W2b' + b2b   (f32 true-order output)
// W2b' rows pre-permuted to packed K order; BN params from stats in block prologue.
__global__ __launch_bounds__(256) void gemm4_node(
    const short* __restrict__ T2p, const float* __restrict__ stats,
    const float* __restrict__ g2, const float* __restrict__ be2,
    const short* __restrict__ Wp, const float* __restrict__ b2b,
    float* __restrict__ out, int N, float invR)
{
    __shared__ float ls_sc[128], ls_sh[128];
    if (threadIdx.x < 128) {
        int c = threadIdx.x;                     // true col
        float mean = stats[c] * invR;
        float var = stats[128 + c] * invR - mean * mean;
        float sc = g2[c] * rsqrtf(var + BN_EPS);
        ls_sc[c] = sc;
        ls_sh[c] = be2[c] - mean * sc;
    }
    __syncthreads();

    const int lane = threadIdx.x & 63, wave = threadIdx.x >> 6;
    const int m0 = blockIdx.x * 128 + wave * 32;
    if (m0 >= N) return;   // N % 32 == 0
    const int lr = lane & 15, lg = lane >> 4;
    const int e0 = m0 + lr, e1 = m0 + 16 + lr;

    f32x4 acc[2][8];
#pragma unroll
    for (int n0 = 0; n0 < 8; ++n0) {
        float bias = b2b[n0 * 16 + lr];
        acc[0][n0] = (f32x4){bias, bias, bias, bias};
        acc[1][n0] = (f32x4){bias, bias, bias, bias};
    }
#pragma unroll
    for (int kb = 0; kb < 4; ++kb) {
        // packed pos p = kb*32+lg*8+j  ->  true col j*16 + kb*4 + lg
        float scl[8], shf[8];
#pragma unroll
        for (int j = 0; j < 8; ++j) {
            int c = j * 16 + kb * 4 + lg;
            scl[j] = ls_sc[c];
            shf[j] = ls_sh[c];
        }
        bfrag r0 = *(const bfrag*)(T2p + (size_t)e0 * 128 + kb * 32 + lg * 8);
        bfrag r1 = *(const bfrag*)(T2p + (size_t)e1 * 128 + kb * 32 + lg * 8);
        bfrag a0, a1;
#pragma unroll
        for (int j = 0; j < 8; ++j) {
            a0[j] = f2bf(selu_f(bf2f(r0[j]) * scl[j] + shf[j]));
            a1[j] = f2bf(selu_f(bf2f(r1[j]) * scl[j] + shf[j]));
        }
        const short* wb = Wp + (size_t)kb * 4096;
#pragma unroll
        for (int n0 = 0; n0 < 8; ++n0) {
            bfrag b = *(const bfrag*)(wb + ((n0 * 16 + lr) * 4 + lg) * 8);
            acc[0][n0] = __builtin_amdgcn_mfma_f32_16x16x32_bf16(a0, b, acc[0][n0], 0, 0, 0);
            acc[1][n0] = __builtin_amdgcn_mfma_f32_16x16x32_bf16(a1, b, acc[1][n0], 0, 0, 0);
        }
    }
#pragma unroll
    for (int t = 0; t < 2; ++t) {
        const int rbase = m0 + t * 16 + lg * 4;
#pragma unroll
        for (int n0 = 0; n0 < 8; ++n0) {
            const int c = n0 * 16 + lr;
#pragma unroll
            for (int r = 0; r < 4; ++r)
                out[(size_t)(rbase + r) * 128 + c] = acc[t][n0][r];
        }
    }
}

// ---------------------------------------------------------------------------
// Workspace layout (bytes):
//   0        Wp1x 32768  | 32768 Wp1e 16384 | 49152 Wp2a 98304 | 147456 Wp2b 32768
//   180224   Wf 65536    | 245760 cb 512
//   246272   stats1 1024 | 247296 stats2 1024
//   250368   CNTi 400000 | 650368 OFF 400000
//   1050368  BSUM 1024   | 1051392 BOFF 1024
//   1052416  SPOS 3200000
//   4252416  Aggm bf16 100000x128 (25600000)
//   29852416 Xap bf16 100000x128 (25600000)  [phase2: T2p overlays]
//   55452416 T1p bf16 800000x128 (204800000)  [CSR-sorted row order]
//   total: 260252416
// ---------------------------------------------------------------------------
extern "C" void kernel_launch(void* const* d_in, const int* in_sizes, int n_in,
                              void* d_out, int out_size, void* d_ws, size_t ws_size,
                              hipStream_t stream)
{
    const float* x   = (const float*)d_in[0];
    const float* ea  = (const float*)d_in[1];
    const float* u   = (const float*)d_in[2];
    const float* W1a = (const float*)d_in[3];
    // d_in[4] = b1a: cancels in BN1
    const float* g1  = (const float*)d_in[5];
    const float* be1 = (const float*)d_in[6];
    const float* W1b = (const float*)d_in[7];
    const float* b1b = (const float*)d_in[8];
    const float* W2a = (const float*)d_in[9];
    // d_in[10] = b2a: cancels in BN2
    const float* g2  = (const float*)d_in[11];
    const float* be2 = (const float*)d_in[12];
    const float* W2b = (const float*)d_in[13];
    const float* b2b = (const float*)d_in[14];
    const int* ei    = (const int*)d_in[15];
    const int* rowI  = ei;
    const int* colI  = ei + N_EDGES;
    const int* batch = (const int*)d_in[16];
    float* out = (float*)d_out;

    if (ws_size < 260252416ull) return;

    char* ws = (char*)d_ws;
    short* Wp1x   = (short*)(ws + 0);
    short* Wp1e   = (short*)(ws + 32768);
    short* Wp2a   = (short*)(ws + 49152);
    short* Wp2b   = (short*)(ws + 147456);
    float* Wf     = (float*)(ws + 180224);
    float* cb     = (float*)(ws + 245760);
    float* stats1 = (float*)(ws + 246272);
    float* stats2 = (float*)(ws + 247296);
    int*   CNTi   = (int*)(ws + 250368);
    int*   OFF    = (int*)(ws + 650368);
    int*   BSUM   = (int*)(ws + 1050368);
    int*   BOFF   = (int*)(ws + 1051392);
    int*   SPOS   = (int*)(ws + 1052416);
    short* Aggm   = (short*)(ws + 4252416);
    short* Xap    = (short*)(ws + 29852416ull);
    short* T2p    = (short*)(ws + 29852416ull);   // overlays Xap (dead after gemm1n)
    short* T1p    = (short*)(ws + 55452416ull);

    hipMemsetAsync(stats1, 0, 2048, stream);      // stats1, stats2
    hipMemsetAsync(CNTi, 0, 400000, stream);

    // weight prep
    pack_w<<<64, 256, 0, stream>>>(W1a, Wp1x, 128);
    pack_w<<<32, 256, 0, stream>>>(W1a + 128 * 128, Wp1e, 64);
    fold_w<<<64, 256, 0, stream>>>(W1b, W2a, Wf);
    fold_b<<<1, 128, 0, stream>>>(b1b, W2a, cb);
    pack_w<<<64, 256, 0, stream>>>(W2a, Wp2a, 128);                  // x block
    pack_w_perm<<<64, 256, 0, stream>>>(Wf, Wp2a + 16384);           // folded middle (perm)
    pack_w<<<64, 256, 0, stream>>>(W2a + 256 * 128, Wp2a + 32768, 128);  // u block
    pack_w_perm<<<64, 256, 0, stream>>>(W2b, Wp2b);                  // perm for packed T2

    // CSR build (SPOS = inverse permutation)
    hist_k<<<(N_EDGES + 255) / 256, 256, 0, stream>>>(colI, CNTi, N_EDGES);
    scan1<<<98, 1024, 0, stream>>>(CNTi, OFF, BSUM, N_NODES);
    scan2<<<1, 128, 0, stream>>>(BSUM, BOFF, 98);
    scan3<<<98, 1024, 0, stream>>>(OFF, BOFF, N_NODES);
    fill_k<<<(N_EDGES + 255) / 256, 256, 0, stream>>>(colI, OFF, SPOS, N_EDGES);

    // node-side half of edge layer 1
    gemmX<<<(N_NODES + 127) / 128, 256, 0, stream>>>(x, Wp1x, Xap, N_NODES);

    // edge layer 1 (natural read order, sorted write order) + stats
    gemm1n<<<N_EDGES / 128, 256, 0, stream>>>(ea, rowI, SPOS, Wp1e, Xap, T1p, stats1, N_EDGES);

    // segmented selu-mean over bucket-contiguous T1p; BN1 inline
    segsel<<<2048, 256, 0, stream>>>(T1p, stats1, g1, be1, OFF, CNTi, Aggm,
                                     N_NODES, 1.0f / (float)N_EDGES);

    // node MLP
    gemm3_node<<<(N_NODES + 127) / 128, 256, 0, stream>>>(x, Aggm, u, batch, CNTi, cb,
                                                          Wp2a, T2p, stats2, N_NODES);
    gemm4_node<<<(N_NODES + 127) / 128, 256, 0, stream>>>(T2p, stats2, g2, be2, Wp2b, b2b,
                                                          out, N_NODES, 1.0f / (float)N_NODES);
}

// Round 7
// 458.254 us; speedup vs baseline: 1.6199x; 1.0192x over previous
//
#include <hip/hip_runtime.h>
#include <hip/hip_bf16.h>
#include <math.h>

// ---------------------------------------------------------------------------
// NodeMLPModel: edge MLP (GEMM+BN+SELU+GEMM) -> scatter-mean -> node MLP.
// Round-7:
//   * prep: ONE kernel packs all weights (fold W1b@W2a computed inline,
//     permuted variants) + cb + col-histogram.  17 -> 11 launches.
//   * gemm1n: grid-stride (2048 blocks), register-accumulated BN stats
//     (one atomic set per block), nontemporal ea loads + T1p stores
//     (keep L2/L3 for the Xap gather working set).
//   * gemm3f: segsel FUSED into node GEMM -- block aggregates its 128
//     nodes' buckets (selu(BN1(.)) means) into padded LDS, then MFMAs
//     from LDS. Aggm buffer + launch eliminated.
//   * gemm4: nontemporal T2p loads / out stores.
// Packed column order p=lr*8+n0 (true col pi(p)=(p&7)*16+(p>>3)) for
// T1p/T2p and the LDS agg tile.
// Fragment layout (m89/m91-verified):
//   A: lane holds A[lane&15][8*(lane>>4)+j]
//   B: lane holds B[8*(lane>>4)+j][lane&15]
//   D: lane holds D[4*(lane>>4)+r][lane&15]
// ---------------------------------------------------------------------------

typedef __attribute__((ext_vector_type(8))) short bfrag;
typedef __attribute__((ext_vector_type(4))) float f32x4;
typedef __attribute__((ext_vector_type(4))) float f4raw;
typedef __attribute__((ext_vector_type(2))) unsigned u32x2;

#define N_EDGES 800000
#define N_NODES 100000
#define BN_EPS 1e-5f

static __device__ __forceinline__ short f2bf(float f) {
    union { float f; unsigned u; } v; v.f = f;
    unsigned r = (v.u + 0x7FFFu + ((v.u >> 16) & 1u)) >> 16;  // RNE
    return (short)r;
}
static __device__ __forceinline__ float bf2f(short h) {
    union { unsigned u; float f; } v;
    v.u = ((unsigned)(unsigned short)h) << 16;
    return v.f;
}
static __device__ __forceinline__ unsigned pack2(float lo, float hi) {
    return ((unsigned)(unsigned short)f2bf(lo)) | (((unsigned)(unsigned short)f2bf(hi)) << 16);
}

static __device__ __forceinline__ bfrag load8f_bf(const float* __restrict__ p) {
    float4 a = *(const float4*)p;
    float4 b = *(const float4*)(p + 4);
    bfrag r;
    r[0] = f2bf(a.x); r[1] = f2bf(a.y); r[2] = f2bf(a.z); r[3] = f2bf(a.w);
    r[4] = f2bf(b.x); r[5] = f2bf(b.y); r[6] = f2bf(b.z); r[7] = f2bf(b.w);
    return r;
}
// nontemporal variants (streaming data: bypass cache retention)
static __device__ __forceinline__ bfrag load8f_bf_nt(const float* __restrict__ p) {
    f4raw a = __builtin_nontemporal_load((const f4raw*)p);
    f4raw b = __builtin_nontemporal_load((const f4raw*)(p + 4));
    bfrag r;
    r[0] = f2bf(a[0]); r[1] = f2bf(a[1]); r[2] = f2bf(a[2]); r[3] = f2bf(a[3]);
    r[4] = f2bf(b[0]); r[5] = f2bf(b[1]); r[6] = f2bf(b[2]); r[7] = f2bf(b[3]);
    return r;
}
static __device__ __forceinline__ u32x2 ldnt_u2(const short* p) {
    return __builtin_nontemporal_load((const u32x2*)p);
}
static __device__ __forceinline__ void stnt_frag(short* p, bfrag v) {
    __builtin_nontemporal_store(v, (bfrag*)p);
}

static __device__ __forceinline__ float selu_f(float v) {
    return v > 0.f ? 1.0507009873554805f * v
                   : 1.7580993408473766f * (__expf(v) - 1.0f);
}

// ---------------------------------------------------------------------------
// prep: all weight packing + cb + histogram in ONE kernel.
// Block ranges:
//   [0,64)    Wp1x   <- W1a[:128]          (pack)
//   [64,96)   Wp1e   <- W1a[128:192]       (pack, K=64)
//   [96,160)  Wp2a.x <- W2a[:128]          (pack)
//   [160,224) Wp2a.m <- (W1b@W2a[128:256]) (fold inline, perm rows)
//   [224,288) Wp2a.u <- W2a[256:384]       (pack)
//   [288,352) Wp2b   <- W2b                (pack, perm rows)
//   [352]     cb[c]  = b1b @ W2a[128:256]
//   [353,...) histogram of colI -> CNTi
static __device__ __forceinline__ void pack_slot(short* __restrict__ Wp, int k, int n, float val) {
    int kb = k >> 5, g = (k >> 3) & 3, j = k & 7;
    Wp[(((size_t)kb * 128 + n) * 4 + g) * 8 + j] = f2bf(val);
}

__global__ void prep(const float* __restrict__ W1a, const float* __restrict__ W1b,
                     const float* __restrict__ b1b, const float* __restrict__ W2a,
                     const float* __restrict__ W2b,
                     short* __restrict__ Wp1x, short* __restrict__ Wp1e,
                     short* __restrict__ Wp2a, short* __restrict__ Wp2b,
                     float* __restrict__ cb,
                     const int* __restrict__ colI, int* __restrict__ CNTi, int E)
{
    const int b = blockIdx.x, t = threadIdx.x;
    if (b < 64) {
        int idx = b * 256 + t; int k = idx >> 7, n = idx & 127;
        pack_slot(Wp1x, k, n, W1a[idx]);
    } else if (b < 96) {
        int idx = (b - 64) * 256 + t; int k = idx >> 7, n = idx & 127;
        pack_slot(Wp1e, k, n, W1a[128 * 128 + idx]);
    } else if (b < 160) {
        int idx = (b - 96) * 256 + t; int k = idx >> 7, n = idx & 127;
        pack_slot(Wp2a, k, n, W2a[idx]);
    } else if (b < 224) {
        int idx = (b - 160) * 256 + t; int k = idx >> 7, n = idx & 127;
        int kt = ((k & 7) << 4) + (k >> 3);       // perm: packed k -> true row
        float s = 0.f;
        for (int j = 0; j < 128; ++j)
            s += W1b[kt * 128 + j] * W2a[(size_t)(128 + j) * 128 + n];
        pack_slot(Wp2a + 16384, k, n, s);
    } else if (b < 288) {
        int idx = (b - 224) * 256 + t; int k = idx >> 7, n = idx & 127;
        pack_slot(Wp2a + 32768, k, n, W2a[(size_t)256 * 128 + idx]);
    } else if (b < 352) {
        int idx = (b - 288) * 256 + t; int k = idx >> 7, n = idx & 127;
        int kt = ((k & 7) << 4) + (k >> 3);
        pack_slot(Wp2b, k, n, W2b[(size_t)kt * 128 + n]);
    } else if (b == 352) {
        if (t < 128) {
            float s = 0.f;
            for (int j = 0; j < 128; ++j) s += b1b[j] * W2a[(size_t)(128 + j) * 128 + t];
            cb[t] = s;
        }
    } else {
        int e = (b - 353) * 256 + t;
        if (e < E) atomicAdd(&CNTi[colI[e]], 1);
    }
}

// ----------------------------- CSR scan + fill ------------------------------
__global__ void scan1(const int* __restrict__ cnt, int* __restrict__ off,
                      int* __restrict__ bsum, int N) {
    __shared__ int ls[1024];
    int i = blockIdx.x * 1024 + threadIdx.x;
    int v = (i < N) ? cnt[i] : 0;
    ls[threadIdx.x] = v;
    __syncthreads();
    for (int d = 1; d < 1024; d <<= 1) {
        int t = (threadIdx.x >= d) ? ls[threadIdx.x - d] : 0;
        __syncthreads();
        ls[threadIdx.x] += t;
        __syncthreads();
    }
    if (i < N) off[i] = ls[threadIdx.x] - v;
    if (threadIdx.x == 1023) bsum[blockIdx.x] = ls[1023];
}

__global__ void scan2(const int* __restrict__ bsum, int* __restrict__ boff, int NB) {
    __shared__ int ls[128];
    int v = (threadIdx.x < NB) ? bsum[threadIdx.x] : 0;
    ls[threadIdx.x] = v;
    __syncthreads();
    for (int d = 1; d < 128; d <<= 1) {
        int t = (threadIdx.x >= d) ? ls[threadIdx.x - d] : 0;
        __syncthreads();
        ls[threadIdx.x] += t;
        __syncthreads();
    }
    if (threadIdx.x < NB) boff[threadIdx.x] = ls[threadIdx.x] - v;
}

__global__ void scan3(int* __restrict__ off, const int* __restrict__ boff, int N) {
    int i = blockIdx.x * 1024 + threadIdx.x;
    if (i < N) off[i] += boff[blockIdx.x];
}

// Consumes OFF (becomes end offsets: beg = OFF[v]-CNTi[v]).
// SPOS[e] = sorted position of edge e (inverse permutation).
__global__ void fill_k(const int* __restrict__ col, int* __restrict__ off,
                       int* __restrict__ spos, int E) {
    int e = blockIdx.x * 256 + threadIdx.x;
    if (e < E) spos[e] = atomicAdd(&off[col[e]], 1);
}

// ---------------------------------------------------------------------------
// gemmX: Xap = packed bf16 of (x @ W1a[:128,:])
// Layout: Xap[v*128 + lr*8 + n0] = Xa[v][n0*16+lr]
__global__ __launch_bounds__(256) void gemmX(
    const float* __restrict__ x, const short* __restrict__ Wp,
    short* __restrict__ Xap, int N)
{
    const int lane = threadIdx.x & 63, wave = threadIdx.x >> 6;
    const int m0 = blockIdx.x * 128 + wave * 32;
    if (m0 >= N) return;  // N % 32 == 0
    const int lr = lane & 15, lg = lane >> 4;
    const int v0 = m0 + lr, v1 = m0 + 16 + lr;

    f32x4 acc[2][8];
#pragma unroll
    for (int t = 0; t < 2; ++t)
#pragma unroll
        for (int n = 0; n < 8; ++n) acc[t][n] = (f32x4){0.f, 0.f, 0.f, 0.f};

#pragma unroll
    for (int kb = 0; kb < 4; ++kb) {
        bfrag a0 = load8f_bf(x + (size_t)v0 * 128 + kb * 32 + lg * 8);
        bfrag a1 = load8f_bf(x + (size_t)v1 * 128 + kb * 32 + lg * 8);
        const short* wb = Wp + (size_t)kb * 4096;
#pragma unroll
        for (int n0 = 0; n0 < 8; ++n0) {
            bfrag b = *(const bfrag*)(wb + ((n0 * 16 + lr) * 4 + lg) * 8);
            acc[0][n0] = __builtin_amdgcn_mfma_f32_16x16x32_bf16(a0, b, acc[0][n0], 0, 0, 0);
            acc[1][n0] = __builtin_amdgcn_mfma_f32_16x16x32_bf16(a1, b, acc[1][n0], 0, 0, 0);
        }
    }
#pragma unroll
    for (int t = 0; t < 2; ++t) {
        const int rbase = m0 + t * 16 + lg * 4;
#pragma unroll
        for (int r = 0; r < 4; ++r) {
            bfrag o;
#pragma unroll
            for (int n0 = 0; n0 < 8; ++n0) o[n0] = f2bf(acc[t][n0][r]);
            *(bfrag*)(Xap + (size_t)(rbase + r) * 128 + lr * 8) = o;
        }
    }
}

// ---------------------------------------------------------------------------
// gemm1n: T1p[SPOS[e]] = packed(ea[e] @ W1a[128:192] + Xa[row[e]])
// Grid-stride tiles; Xap gathers hoisted; nontemporal ea loads + T1p stores;
// BN stats accumulated in registers across tiles, one atomic set per block.
__global__ __launch_bounds__(256) void gemm1n(
    const float* __restrict__ ea, const int* __restrict__ rowI,
    const int* __restrict__ SPOS, const short* __restrict__ Wp,
    const short* __restrict__ Xap, short* __restrict__ T1p,
    float* __restrict__ stats, int E)
{
    const int lane = threadIdx.x & 63, wave = threadIdx.x >> 6;
    const int lr = lane & 15, lg = lane >> 4;

    float ps[8], qs[8];
#pragma unroll
    for (int n0 = 0; n0 < 8; ++n0) { ps[n0] = 0.f; qs[n0] = 0.f; }

    const int NT = E >> 7;   // E % 128 == 0
    for (int tile = blockIdx.x; tile < NT; tile += gridDim.x) {
        const int m0 = tile * 128 + wave * 32;

        // hoisted: indices + Xa gathers (latency hidden under ea loads+MFMA)
        int spos[2][4];
        bfrag xa[2][4];
#pragma unroll
        for (int t = 0; t < 2; ++t) {
            const int rbase = m0 + t * 16 + lg * 4;
#pragma unroll
            for (int r = 0; r < 4; ++r) {
                const int e = rbase + r;
                spos[t][r] = SPOS[e];
                xa[t][r] = *(const bfrag*)(Xap + (size_t)rowI[e] * 128 + lr * 8);
            }
        }

        const float* er0 = ea + (size_t)(m0 + lr) * 64;
        const float* er1 = ea + (size_t)(m0 + 16 + lr) * 64;

        f32x4 acc[2][8];
#pragma unroll
        for (int t = 0; t < 2; ++t)
#pragma unroll
            for (int n = 0; n < 8; ++n) acc[t][n] = (f32x4){0.f, 0.f, 0.f, 0.f};

#pragma unroll
        for (int kb = 0; kb < 2; ++kb) {
            bfrag a0 = load8f_bf_nt(er0 + kb * 32 + lg * 8);
            bfrag a1 = load8f_bf_nt(er1 + kb * 32 + lg * 8);
            const short* wb = Wp + (size_t)kb * 4096;
#pragma unroll
            for (int n0 = 0; n0 < 8; ++n0) {
                bfrag b = *(const bfrag*)(wb + ((n0 * 16 + lr) * 4 + lg) * 8);
                acc[0][n0] = __builtin_amdgcn_mfma_f32_16x16x32_bf16(a0, b, acc[0][n0], 0, 0, 0);
                acc[1][n0] = __builtin_amdgcn_mfma_f32_16x16x32_bf16(a1, b, acc[1][n0], 0, 0, 0);
            }
        }

        // epilogue: add gathered Xa, accumulate stats, scatter-store (256B segs)
#pragma unroll
        for (int t = 0; t < 2; ++t) {
#pragma unroll
            for (int r = 0; r < 4; ++r) {
                bfrag o;
#pragma unroll
                for (int n0 = 0; n0 < 8; ++n0) {
                    float v = acc[t][n0][r] + bf2f(xa[t][r][n0]);
                    ps[n0] += v; qs[n0] += v * v;
                    o[n0] = f2bf(v);
                }
                stnt_frag(T1p + (size_t)spos[t][r] * 128 + lr * 8, o);
            }
        }
    }

    // one stats reduction per block
    __shared__ float ls[256];
    ls[threadIdx.x] = 0.f;
    __syncthreads();
#pragma unroll
    for (int n0 = 0; n0 < 8; ++n0) {
        const int c = n0 * 16 + lr;
        float p = ps[n0], q = qs[n0];
        p += __shfl_xor(p, 16); p += __shfl_xor(p, 32);
        q += __shfl_xor(q, 16); q += __shfl_xor(q, 32);
        if (lg == 0) { atomicAdd(&ls[c], p); atomicAdd(&ls[128 + c], q); }
    }
    __syncthreads();
    atomicAdd(&stats[threadIdx.x], ls[threadIdx.x]);
}

// ---------------------------------------------------------------------------
// gemm3f: fused segsel + node GEMM.
// Phase A: each wave aggregates 32 of the block's 128 nodes:
//   aggL[nl] = packed bf16 of (1/max(deg,1)) * sum_{bucket} selu(BN1(T1p row))
// Phase B: T2p = packed([x, aggL, u[batch]] @ W2a' + (deg>0)*cb); fused stats2.
__global__ __launch_bounds__(256) void gemm3f(
    const float* __restrict__ x, const short* __restrict__ T1p,
    const float* __restrict__ stats1, const float* __restrict__ g1,
    const float* __restrict__ be1,
    const int* __restrict__ OFF, const int* __restrict__ CNTi,
    const float* __restrict__ u, const int* __restrict__ batch,
    const float* __restrict__ cb, const short* __restrict__ Wp,
    short* __restrict__ T2p, float* __restrict__ stats2,
    int N, float invE)
{
    __shared__ short aggL[128][136];          // 272B pitch: 2-way-free b128 reads
    __shared__ float ls[256];
    __shared__ float ls_sc[128], ls_sh[128];
    ls[threadIdx.x] = 0.f;
    if (threadIdx.x < 128) {
        int p = threadIdx.x;
        int c = ((p & 7) << 4) + (p >> 3);    // packed pos -> true col
        float mean = stats1[c] * invE;
        float var = stats1[128 + c] * invE - mean * mean;
        float sc = g1[c] * rsqrtf(var + BN_EPS);
        ls_sc[p] = sc;
        ls_sh[p] = be1[c] - mean * sc;
    }
    __syncthreads();

    const int lane = threadIdx.x & 63, wave = threadIdx.x >> 6;
    const int m0b = blockIdx.x * 128;

    // ---- Phase A: aggregation into LDS
    {
        const int h = lane >> 5, t = lane & 31;
        const float sc0 = ls_sc[t * 4 + 0], sc1 = ls_sc[t * 4 + 1];
        const float sc2 = ls_sc[t * 4 + 2], sc3 = ls_sc[t * 4 + 3];
        const float sh0 = ls_sh[t * 4 + 0], sh1 = ls_sh[t * 4 + 1];
        const float sh2 = ls_sh[t * 4 + 2], sh3 = ls_sh[t * 4 + 3];
        for (int i = 0; i < 32; ++i) {
            const int v = m0b + wave * 32 + i;
            if (v >= N) break;                 // wave-uniform
            const int cnt = CNTi[v];
            const int beg = OFF[v] - cnt;      // fill_k advanced OFF to end
            const short* base = T1p + (size_t)beg * 128 + t * 4;
            float a0 = 0.f, a1 = 0.f, a2 = 0.f, a3 = 0.f;
            int j = 0;
            for (; j + 4 <= cnt; j += 4) {
                u32x2 wA = ldnt_u2(base + (size_t)(j + h) * 128);
                u32x2 wB = ldnt_u2(base + (size_t)(j + 2 + h) * 128);
                a0 += selu_f(sc0 * bf2f((short)(wA[0] & 0xffff)) + sh0);
                a1 += selu_f(sc1 * bf2f((short)(wA[0] >> 16)) + sh1);
                a2 += selu_f(sc2 * bf2f((short)(wA[1] & 0xffff)) + sh2);
                a3 += selu_f(sc3 * bf2f((short)(wA[1] >> 16)) + sh3);
                a0 += selu_f(sc0 * bf2f((short)(wB[0] & 0xffff)) + sh0);
                a1 += selu_f(sc1 * bf2f((short)(wB[0] >> 16)) + sh1);
                a2 += selu_f(sc2 * bf2f((short)(wB[1] & 0xffff)) + sh2);
                a3 += selu_f(sc3 * bf2f((short)(wB[1] >> 16)) + sh3);
            }
            for (; j < cnt; j += 2) {
                if (j + h < cnt) {
                    u32x2 w = ldnt_u2(base + (size_t)(j + h) * 128);
                    a0 += selu_f(sc0 * bf2f((short)(w[0] & 0xffff)) + sh0);
                    a1 += selu_f(sc1 * bf2f((short)(w[0] >> 16)) + sh1);
                    a2 += selu_f(sc2 * bf2f((short)(w[1] & 0xffff)) + sh2);
                    a3 += selu_f(sc3 * bf2f((short)(w[1] >> 16)) + sh3);
                }
            }
            a0 += __shfl_xor(a0, 32); a1 += __shfl_xor(a1, 32);
            a2 += __shfl_xor(a2, 32); a3 += __shfl_xor(a3, 32);
            if (h == 0) {
                const float inv = 1.0f / fmaxf((float)cnt, 1.0f);
                u32x2 o;
                o[0] = pack2(a0 * inv, a1 * inv);
                o[1] = pack2(a2 * inv, a3 * inv);
                *(u32x2*)&aggL[wave * 32 + i][t * 4] = o;
            }
        }
    }
    __syncthreads();

    // ---- Phase B: node GEMM
    const int m0 = m0b + wave * 32;
    const bool active = (m0 < N);   // N % 32 == 0
    const int lr = lane & 15, lg = lane >> 4;

    if (active) {
        const int v0 = m0 + lr, v1 = m0 + 16 + lr;
        const float* u0 = u + (size_t)batch[v0] * 128;
        const float* u1 = u + (size_t)batch[v1] * 128;

        f32x4 acc[2][8];
#pragma unroll
        for (int t = 0; t < 2; ++t)
#pragma unroll
            for (int n = 0; n < 8; ++n) acc[t][n] = (f32x4){0.f, 0.f, 0.f, 0.f};

#pragma unroll
        for (int kb = 0; kb < 12; ++kb) {
            bfrag a0, a1;
            if (kb >= 4 && kb < 8) {
                a0 = *(const bfrag*)&aggL[wave * 32 + lr][(kb - 4) * 32 + lg * 8];
                a1 = *(const bfrag*)&aggL[wave * 32 + 16 + lr][(kb - 4) * 32 + lg * 8];
            } else {
                const float *p0, *p1;
                if (kb < 4) {
                    p0 = x + (size_t)v0 * 128 + kb * 32 + lg * 8;
                    p1 = x + (size_t)v1 * 128 + kb * 32 + lg * 8;
                } else {
                    p0 = u0 + (kb - 8) * 32 + lg * 8;
                    p1 = u1 + (kb - 8) * 32 + lg * 8;
                }
                a0 = load8f_bf(p0);
                a1 = load8f_bf(p1);
            }
            const short* wb = Wp + (size_t)kb * 4096;
#pragma unroll
            for (int n0 = 0; n0 < 8; ++n0) {
                bfrag b = *(const bfrag*)(wb + ((n0 * 16 + lr) * 4 + lg) * 8);
                acc[0][n0] = __builtin_amdgcn_mfma_f32_16x16x32_bf16(a0, b, acc[0][n0], 0, 0, 0);
                acc[1][n0] = __builtin_amdgcn_mfma_f32_16x16x32_bf16(a1, b, acc[1][n0], 0, 0, 0);
            }
        }
        // epilogue: + flag*cb, stats, packed store
        float cbl[8];
#pragma unroll
        for (int n0 = 0; n0 < 8; ++n0) cbl[n0] = cb[n0 * 16 + lr];
        float ps[8], qs[8];
#pragma unroll
        for (int n0 = 0; n0 < 8; ++n0) { ps[n0] = 0.f; qs[n0] = 0.f; }
#pragma unroll
        for (int t = 0; t < 2; ++t) {
            const int rbase = m0 + t * 16 + lg * 4;
            float fl[4];
#pragma unroll
            for (int r = 0; r < 4; ++r) fl[r] = (CNTi[rbase + r] > 0) ? 1.f : 0.f;
#pragma unroll
            for (int r = 0; r < 4; ++r) {
                bfrag o;
#pragma unroll
                for (int n0 = 0; n0 < 8; ++n0) {
                    float v = acc[t][n0][r] + fl[r] * cbl[n0];
                    ps[n0] += v; qs[n0] += v * v;
                    o[n0] = f2bf(v);
                }
                *(bfrag*)(T2p + (size_t)(rbase + r) * 128 + lr * 8) = o;
            }
        }
#pragma unroll
        for (int n0 = 0; n0 < 8; ++n0) {
            const int c = n0 * 16 + lr;
            float p = ps[n0], q = qs[n0];
            p += __shfl_xor(p, 16); p += __shfl_xor(p, 32);
            q += __shfl_xor(q, 16); q += __shfl_xor(q, 32);
            if (lg == 0) { atomicAdd(&ls[c], p); atomicAdd(&ls[128 + c], q); }
        }
    }
    __syncthreads();
    atomicAdd(&stats2[threadIdx.x], ls[threadIdx.x]);
}

// Node GEMM2: out = selu(BN2(T2p)) @ W2b' + b2b   (f32 true-order output)
__global__ __launch_bounds__(256) void gemm4_node(
    const short* __restrict__ T2p, const float* __restrict__ stats,
    const float* __restrict__ g2, const float* __restrict__ be2,
    const short* __restrict__ Wp, const float* __restrict__ b2b,
    float* __restrict__ out, int N, float invR)
{
    __shared__ float ls_sc[128], ls_sh[128];
    if (threadIdx.x < 128) {
        int c = threadIdx.x;                     // true col
        float mean = stats[c] * invR;
        float var = stats[128 + c] * invR - mean * mean;
        float sc = g2[c] * rsqrtf(var + BN_EPS);
        ls_sc[c] = sc;
        ls_sh[c] = be2[c] - mean * sc;
    }
    __syncthreads();

    const int lane = threadIdx.x & 63, wave = threadIdx.x >> 6;
    const int m0 = blockIdx.x * 128 + wave * 32;
    if (m0 >= N) return;   // N % 32 == 0
    const int lr = lane & 15, lg = lane >> 4;
    const int e0 = m0 + lr, e1 = m0 + 16 + lr;

    f32x4 acc[2][8];
#pragma unroll
    for (int n0 = 0; n0 < 8; ++n0) {
        float bias = b2b[n0 * 16 + lr];
        acc[0][n0] = (f32x4){bias, bias, bias, bias};
        acc[1][n0] = (f32x4){bias, bias, bias, bias};
    }
#pragma unroll
    for (int kb = 0; kb < 4; ++kb) {
        // packed pos p = kb*32+lg*8+j  ->  true col j*16 + kb*4 + lg
        float scl[8], shf[8];
#pragma unroll
        for (int j = 0; j < 8; ++j) {
            int c = j * 16 + kb * 4 + lg;
            scl[j] = ls_sc[c];
            shf[j] = ls_sh[c];
        }
        bfrag r0 = *(const bfrag*)(T2p + (size_t)e0 * 128 + kb * 32 + lg * 8);
        bfrag r1 = *(const bfrag*)(T2p + (size_t)e1 * 128 + kb * 32 + lg * 8);
        bfrag a0, a1;
#pragma unroll
        for (int j = 0; j < 8; ++j) {
            a0[j] = f2bf(selu_f(bf2f(r0[j]) * scl[j] + shf[j]));
            a1[j] = f2bf(selu_f(bf2f(r1[j]) * scl[j] + shf[j]));
        }
        const short* wb = Wp + (size_t)kb * 4096;
#pragma unroll
        for (int n0 = 0; n0 < 8; ++n0) {
            bfrag b = *(const bfrag*)(wb + ((n0 * 16 + lr) * 4 + lg) * 8);
            acc[0][n0] = __builtin_amdgcn_mfma_f32_16x16x32_bf16(a0, b, acc[0][n0], 0, 0, 0);
            acc[1][n0] = __builtin_amdgcn_mfma_f32_16x16x32_bf16(a1, b, acc[1][n0], 0, 0, 0);
        }
    }
#pragma unroll
    for (int t = 0; t < 2; ++t) {
        const int rbase = m0 + t * 16 + lg * 4;
#pragma unroll
        for (int n0 = 0; n0 < 8; ++n0) {
            const int c = n0 * 16 + lr;
#pragma unroll
            for (int r = 0; r < 4; ++r)
                __builtin_nontemporal_store(acc[t][n0][r],
                    out + (size_t)(rbase + r) * 128 + c);
        }
    }
}

// ---------------------------------------------------------------------------
// Workspace layout (bytes):
//   0        Wp1x 32768  | 32768 Wp1e 16384 | 49152 Wp2a 98304 | 147456 Wp2b 32768
//   245760   cb 512
//   246272   stats1 1024 | 247296 stats2 1024
//   250368   CNTi 400000 | 650368 OFF 400000
//   1050368  BSUM 1024   | 1051392 BOFF 1024
//   1052416  SPOS 3200000
//   29852416 Xap bf16 100000x128 (25600000)  [phase2: T2p overlays]
//   55452416 T1p bf16 800000x128 (204800000)  [CSR-sorted row order]
//   total: 260252416
// ---------------------------------------------------------------------------
extern "C" void kernel_launch(void* const* d_in, const int* in_sizes, int n_in,
                              void* d_out, int out_size, void* d_ws, size_t ws_size,
                              hipStream_t stream)
{
    const float* x   = (const float*)d_in[0];
    const float* ea  = (const float*)d_in[1];
    const float* u   = (const float*)d_in[2];
    const float* W1a = (const float*)d_in[3];
    // d_in[4] = b1a: cancels in BN1
    const float* g1  = (const float*)d_in[5];
    const float* be1 = (const float*)d_in[6];
    const float* W1b = (const float*)d_in[7];
    const float* b1b = (const float*)d_in[8];
    const float* W2a = (const float*)d_in[9];
    // d_in[10] = b2a: cancels in BN2
    const float* g2  = (const float*)d_in[11];
    const float* be2 = (const float*)d_in[12];
    const float* W2b = (const float*)d_in[13];
    const float* b2b = (const float*)d_in[14];
    const int* ei    = (const int*)d_in[15];
    const int* rowI  = ei;
    const int* colI  = ei + N_EDGES;
    const int* batch = (const int*)d_in[16];
    float* out = (float*)d_out;

    if (ws_size < 260252416ull) return;

    char* ws = (char*)d_ws;
    short* Wp1x   = (short*)(ws + 0);
    short* Wp1e   = (short*)(ws + 32768);
    short* Wp2a   = (short*)(ws + 49152);
    short* Wp2b   = (short*)(ws + 147456);
    float* cb     = (float*)(ws + 245760);
    float* stats1 = (float*)(ws + 246272);
    float* stats2 = (float*)(ws + 247296);
    int*   CNTi   = (int*)(ws + 250368);
    int*   OFF    = (int*)(ws + 650368);
    int*   BSUM   = (int*)(ws + 1050368);
    int*   BOFF   = (int*)(ws + 1051392);
    int*   SPOS   = (int*)(ws + 1052416);
    short* Xap    = (short*)(ws + 29852416ull);
    short* T2p    = (short*)(ws + 29852416ull);   // overlays Xap (dead after gemm1n)
    short* T1p    = (short*)(ws + 55452416ull);

    hipMemsetAsync(stats1, 0, 2048, stream);      // stats1, stats2
    hipMemsetAsync(CNTi, 0, 400000, stream);

    // all weight prep + histogram: one kernel
    prep<<<353 + (N_EDGES + 255) / 256, 256, 0, stream>>>(
        W1a, W1b, b1b, W2a, W2b, Wp1x, Wp1e, Wp2a, Wp2b, cb, colI, CNTi, N_EDGES);

    // CSR scan + inverse-perm fill
    scan1<<<98, 1024, 0, stream>>>(CNTi, OFF, BSUM, N_NODES);
    scan2<<<1, 128, 0, stream>>>(BSUM, BOFF, 98);
    scan3<<<98, 1024, 0, stream>>>(OFF, BOFF, N_NODES);
    fill_k<<<(N_EDGES + 255) / 256, 256, 0, stream>>>(colI, OFF, SPOS, N_EDGES);

    // node-side half of edge layer 1
    gemmX<<<(N_NODES + 127) / 128, 256, 0, stream>>>(x, Wp1x, Xap, N_NODES);

    // edge layer 1 (natural read order, sorted write order) + stats
    gemm1n<<<2048, 256, 0, stream>>>(ea, rowI, SPOS, Wp1e, Xap, T1p, stats1, N_EDGES);

    // fused segsel + node GEMM1
    gemm3f<<<(N_NODES + 127) / 128, 256, 0, stream>>>(
        x, T1p, stats1, g1, be1, OFF, CNTi, u, batch, cb, Wp2a, T2p, stats2,
        N_NODES, 1.0f / (float)N_EDGES);

    // node GEMM2
    gemm4_node<<<(N_NODES + 127) / 128, 256, 0, stream>>>(T2p, stats2, g2, be2, Wp2b, b2b,
                                                          out, N_NODES, 1.0f / (float)N_NODES);
}

// Round 8
// 370.345 us; speedup vs baseline: 2.0044x; 1.2374x over previous
//
#include <hip/hip_runtime.h>
#include <hip/hip_bf16.h>
#include <math.h>

// ---------------------------------------------------------------------------
// NodeMLPModel: edge MLP (GEMM+BN+SELU+GEMM) -> scatter-mean -> node MLP.
// Round-8: R7 minus the gemm3 fusion (which cut occupancy to 16% and cost
// +100us). segsel back to standalone grid-stride kernel (2048 blocks); gemm3
// back to lean GEMM reading packed Aggm. Keeps R7's single prep kernel,
// grid-strided gemm1n with register BN stats + nontemporal streams.
// Packed column order p=lr*8+n0 (true col pi(p)=(p&7)*16+(p>>3)) for
// T1p/Aggm/T2p.
// Fragment layout (m89/m91-verified):
//   A: lane holds A[lane&15][8*(lane>>4)+j]
//   B: lane holds B[8*(lane>>4)+j][lane&15]
//   D: lane holds D[4*(lane>>4)+r][lane&15]
// ---------------------------------------------------------------------------

typedef __attribute__((ext_vector_type(8))) short bfrag;
typedef __attribute__((ext_vector_type(4))) float f32x4;
typedef __attribute__((ext_vector_type(4))) float f4raw;
typedef __attribute__((ext_vector_type(2))) unsigned u32x2;

#define N_EDGES 800000
#define N_NODES 100000
#define BN_EPS 1e-5f

static __device__ __forceinline__ short f2bf(float f) {
    union { float f; unsigned u; } v; v.f = f;
    unsigned r = (v.u + 0x7FFFu + ((v.u >> 16) & 1u)) >> 16;  // RNE
    return (short)r;
}
static __device__ __forceinline__ float bf2f(short h) {
    union { unsigned u; float f; } v;
    v.u = ((unsigned)(unsigned short)h) << 16;
    return v.f;
}
static __device__ __forceinline__ unsigned pack2(float lo, float hi) {
    return ((unsigned)(unsigned short)f2bf(lo)) | (((unsigned)(unsigned short)f2bf(hi)) << 16);
}

static __device__ __forceinline__ bfrag load8f_bf(const float* __restrict__ p) {
    float4 a = *(const float4*)p;
    float4 b = *(const float4*)(p + 4);
    bfrag r;
    r[0] = f2bf(a.x); r[1] = f2bf(a.y); r[2] = f2bf(a.z); r[3] = f2bf(a.w);
    r[4] = f2bf(b.x); r[5] = f2bf(b.y); r[6] = f2bf(b.z); r[7] = f2bf(b.w);
    return r;
}
// nontemporal variants (streaming data: bypass cache retention)
static __device__ __forceinline__ bfrag load8f_bf_nt(const float* __restrict__ p) {
    f4raw a = __builtin_nontemporal_load((const f4raw*)p);
    f4raw b = __builtin_nontemporal_load((const f4raw*)(p + 4));
    bfrag r;
    r[0] = f2bf(a[0]); r[1] = f2bf(a[1]); r[2] = f2bf(a[2]); r[3] = f2bf(a[3]);
    r[4] = f2bf(b[0]); r[5] = f2bf(b[1]); r[6] = f2bf(b[2]); r[7] = f2bf(b[3]);
    return r;
}
static __device__ __forceinline__ u32x2 ldnt_u2(const short* p) {
    return __builtin_nontemporal_load((const u32x2*)p);
}
static __device__ __forceinline__ void stnt_frag(short* p, bfrag v) {
    __builtin_nontemporal_store(v, (bfrag*)p);
}

static __device__ __forceinline__ float selu_f(float v) {
    return v > 0.f ? 1.0507009873554805f * v
                   : 1.7580993408473766f * (__expf(v) - 1.0f);
}

// ---------------------------------------------------------------------------
// prep: all weight packing + cb + histogram in ONE kernel.
static __device__ __forceinline__ void pack_slot(short* __restrict__ Wp, int k, int n, float val) {
    int kb = k >> 5, g = (k >> 3) & 3, j = k & 7;
    Wp[(((size_t)kb * 128 + n) * 4 + g) * 8 + j] = f2bf(val);
}

__global__ void prep(const float* __restrict__ W1a, const float* __restrict__ W1b,
                     const float* __restrict__ b1b, const float* __restrict__ W2a,
                     const float* __restrict__ W2b,
                     short* __restrict__ Wp1x, short* __restrict__ Wp1e,
                     short* __restrict__ Wp2a, short* __restrict__ Wp2b,
                     float* __restrict__ cb,
                     const int* __restrict__ colI, int* __restrict__ CNTi, int E)
{
    const int b = blockIdx.x, t = threadIdx.x;
    if (b < 64) {
        int idx = b * 256 + t; int k = idx >> 7, n = idx & 127;
        pack_slot(Wp1x, k, n, W1a[idx]);
    } else if (b < 96) {
        int idx = (b - 64) * 256 + t; int k = idx >> 7, n = idx & 127;
        pack_slot(Wp1e, k, n, W1a[128 * 128 + idx]);
    } else if (b < 160) {
        int idx = (b - 96) * 256 + t; int k = idx >> 7, n = idx & 127;
        pack_slot(Wp2a, k, n, W2a[idx]);
    } else if (b < 224) {
        int idx = (b - 160) * 256 + t; int k = idx >> 7, n = idx & 127;
        int kt = ((k & 7) << 4) + (k >> 3);       // perm: packed k -> true row
        float s = 0.f;
        for (int j = 0; j < 128; ++j)
            s += W1b[kt * 128 + j] * W2a[(size_t)(128 + j) * 128 + n];
        pack_slot(Wp2a + 16384, k, n, s);
    } else if (b < 288) {
        int idx = (b - 224) * 256 + t; int k = idx >> 7, n = idx & 127;
        pack_slot(Wp2a + 32768, k, n, W2a[(size_t)256 * 128 + idx]);
    } else if (b < 352) {
        int idx = (b - 288) * 256 + t; int k = idx >> 7, n = idx & 127;
        int kt = ((k & 7) << 4) + (k >> 3);
        pack_slot(Wp2b, k, n, W2b[(size_t)kt * 128 + n]);
    } else if (b == 352) {
        if (t < 128) {
            float s = 0.f;
            for (int j = 0; j < 128; ++j) s += b1b[j] * W2a[(size_t)(128 + j) * 128 + t];
            cb[t] = s;
        }
    } else {
        int e = (b - 353) * 256 + t;
        if (e < E) atomicAdd(&CNTi[colI[e]], 1);
    }
}

// ----------------------------- CSR scan + fill ------------------------------
__global__ void scan1(const int* __restrict__ cnt, int* __restrict__ off,
                      int* __restrict__ bsum, int N) {
    __shared__ int ls[1024];
    int i = blockIdx.x * 1024 + threadIdx.x;
    int v = (i < N) ? cnt[i] : 0;
    ls[threadIdx.x] = v;
    __syncthreads();
    for (int d = 1; d < 1024; d <<= 1) {
        int t = (threadIdx.x >= d) ? ls[threadIdx.x - d] : 0;
        __syncthreads();
        ls[threadIdx.x] += t;
        __syncthreads();
    }
    if (i < N) off[i] = ls[threadIdx.x] - v;
    if (threadIdx.x == 1023) bsum[blockIdx.x] = ls[1023];
}

__global__ void scan2(const int* __restrict__ bsum, int* __restrict__ boff, int NB) {
    __shared__ int ls[128];
    int v = (threadIdx.x < NB) ? bsum[threadIdx.x] : 0;
    ls[threadIdx.x] = v;
    __syncthreads();
    for (int d = 1; d < 128; d <<= 1) {
        int t = (threadIdx.x >= d) ? ls[threadIdx.x - d] : 0;
        __syncthreads();
        ls[threadIdx.x] += t;
        __syncthreads();
    }
    if (threadIdx.x < NB) boff[threadIdx.x] = ls[threadIdx.x] - v;
}

__global__ void scan3(int* __restrict__ off, const int* __restrict__ boff, int N) {
    int i = blockIdx.x * 1024 + threadIdx.x;
    if (i < N) off[i] += boff[blockIdx.x];
}

// Consumes OFF (becomes end offsets: beg = OFF[v]-CNTi[v]).
// SPOS[e] = sorted position of edge e (inverse permutation).
__global__ void fill_k(const int* __restrict__ col, int* __restrict__ off,
                       int* __restrict__ spos, int E) {
    int e = blockIdx.x * 256 + threadIdx.x;
    if (e < E) spos[e] = atomicAdd(&off[col[e]], 1);
}

// ---------------------------------------------------------------------------
// gemmX: Xap = packed bf16 of (x @ W1a[:128,:])
// Layout: Xap[v*128 + lr*8 + n0] = Xa[v][n0*16+lr]
__global__ __launch_bounds__(256) void gemmX(
    const float* __restrict__ x, const short* __restrict__ Wp,
    short* __restrict__ Xap, int N)
{
    const int lane = threadIdx.x & 63, wave = threadIdx.x >> 6;
    const int m0 = blockIdx.x * 128 + wave * 32;
    if (m0 >= N) return;  // N % 32 == 0
    const int lr = lane & 15, lg = lane >> 4;
    const int v0 = m0 + lr, v1 = m0 + 16 + lr;

    f32x4 acc[2][8];
#pragma unroll
    for (int t = 0; t < 2; ++t)
#pragma unroll
        for (int n = 0; n < 8; ++n) acc[t][n] = (f32x4){0.f, 0.f, 0.f, 0.f};

#pragma unroll
    for (int kb = 0; kb < 4; ++kb) {
        bfrag a0 = load8f_bf(x + (size_t)v0 * 128 + kb * 32 + lg * 8);
        bfrag a1 = load8f_bf(x + (size_t)v1 * 128 + kb * 32 + lg * 8);
        const short* wb = Wp + (size_t)kb * 4096;
#pragma unroll
        for (int n0 = 0; n0 < 8; ++n0) {
            bfrag b = *(const bfrag*)(wb + ((n0 * 16 + lr) * 4 + lg) * 8);
            acc[0][n0] = __builtin_amdgcn_mfma_f32_16x16x32_bf16(a0, b, acc[0][n0], 0, 0, 0);
            acc[1][n0] = __builtin_amdgcn_mfma_f32_16x16x32_bf16(a1, b, acc[1][n0], 0, 0, 0);
        }
    }
#pragma unroll
    for (int t = 0; t < 2; ++t) {
        const int rbase = m0 + t * 16 + lg * 4;
#pragma unroll
        for (int r = 0; r < 4; ++r) {
            bfrag o;
#pragma unroll
            for (int n0 = 0; n0 < 8; ++n0) o[n0] = f2bf(acc[t][n0][r]);
            *(bfrag*)(Xap + (size_t)(rbase + r) * 128 + lr * 8) = o;
        }
    }
}

// ---------------------------------------------------------------------------
// gemm1n: T1p[SPOS[e]] = packed(ea[e] @ W1a[128:192] + Xa[row[e]])
// Grid-stride tiles; Xap gathers hoisted; nontemporal ea loads + T1p stores;
// BN stats accumulated in registers across tiles, one atomic set per block.
__global__ __launch_bounds__(256) void gemm1n(
    const float* __restrict__ ea, const int* __restrict__ rowI,
    const int* __restrict__ SPOS, const short* __restrict__ Wp,
    const short* __restrict__ Xap, short* __restrict__ T1p,
    float* __restrict__ stats, int E)
{
    const int lane = threadIdx.x & 63, wave = threadIdx.x >> 6;
    const int lr = lane & 15, lg = lane >> 4;

    float ps[8], qs[8];
#pragma unroll
    for (int n0 = 0; n0 < 8; ++n0) { ps[n0] = 0.f; qs[n0] = 0.f; }

    const int NT = E >> 7;   // E % 128 == 0
    for (int tile = blockIdx.x; tile < NT; tile += gridDim.x) {
        const int m0 = tile * 128 + wave * 32;

        // hoisted: indices + Xa gathers (latency hidden under ea loads+MFMA)
        int spos[2][4];
        bfrag xa[2][4];
#pragma unroll
        for (int t = 0; t < 2; ++t) {
            const int rbase = m0 + t * 16 + lg * 4;
#pragma unroll
            for (int r = 0; r < 4; ++r) {
                const int e = rbase + r;
                spos[t][r] = SPOS[e];
                xa[t][r] = *(const bfrag*)(Xap + (size_t)rowI[e] * 128 + lr * 8);
            }
        }

        const float* er0 = ea + (size_t)(m0 + lr) * 64;
        const float* er1 = ea + (size_t)(m0 + 16 + lr) * 64;

        f32x4 acc[2][8];
#pragma unroll
        for (int t = 0; t < 2; ++t)
#pragma unroll
            for (int n = 0; n < 8; ++n) acc[t][n] = (f32x4){0.f, 0.f, 0.f, 0.f};

#pragma unroll
        for (int kb = 0; kb < 2; ++kb) {
            bfrag a0 = load8f_bf_nt(er0 + kb * 32 + lg * 8);
            bfrag a1 = load8f_bf_nt(er1 + kb * 32 + lg * 8);
            const short* wb = Wp + (size_t)kb * 4096;
#pragma unroll
            for (int n0 = 0; n0 < 8; ++n0) {
                bfrag b = *(const bfrag*)(wb + ((n0 * 16 + lr) * 4 + lg) * 8);
                acc[0][n0] = __builtin_amdgcn_mfma_f32_16x16x32_bf16(a0, b, acc[0][n0], 0, 0, 0);
                acc[1][n0] = __builtin_amdgcn_mfma_f32_16x16x32_bf16(a1, b, acc[1][n0], 0, 0, 0);
            }
        }

        // epilogue: add gathered Xa, accumulate stats, scatter-store (256B segs)
#pragma unroll
        for (int t = 0; t < 2; ++t) {
#pragma unroll
            for (int r = 0; r < 4; ++r) {
                bfrag o;
#pragma unroll
                for (int n0 = 0; n0 < 8; ++n0) {
                    float v = acc[t][n0][r] + bf2f(xa[t][r][n0]);
                    ps[n0] += v; qs[n0] += v * v;
                    o[n0] = f2bf(v);
                }
                stnt_frag(T1p + (size_t)spos[t][r] * 128 + lr * 8, o);
            }
        }
    }

    // one stats reduction per block
    __shared__ float ls[256];
    ls[threadIdx.x] = 0.f;
    __syncthreads();
#pragma unroll
    for (int n0 = 0; n0 < 8; ++n0) {
        const int c = n0 * 16 + lr;
        float p = ps[n0], q = qs[n0];
        p += __shfl_xor(p, 16); p += __shfl_xor(p, 32);
        q += __shfl_xor(q, 16); q += __shfl_xor(q, 32);
        if (lg == 0) { atomicAdd(&ls[c], p); atomicAdd(&ls[128 + c], q); }
    }
    __syncthreads();
    atomicAdd(&stats[threadIdx.x], ls[threadIdx.x]);
}

// ---------------------------------------------------------------------------
// segsel: Aggm[v] (packed) = (1/max(deg,1)) * sum_{rows in bucket(v)} selu(BN1(T1p))
// T1p is bucket-contiguous -> pure sequential nt reads. Half-wave per row,
// contiguous node chunks per wave. BN params from stats in block prologue.
__global__ __launch_bounds__(256) void segsel(
    const short* __restrict__ T1p, const float* __restrict__ stats,
    const float* __restrict__ g1, const float* __restrict__ be1,
    const int* __restrict__ OFF, const int* __restrict__ CNTi,
    short* __restrict__ Aggm, int N, float invR)
{
    __shared__ float ls_sc[128], ls_sh[128];
    if (threadIdx.x < 128) {
        int p = threadIdx.x;
        int c = ((p & 7) << 4) + (p >> 3);       // true col
        float mean = stats[c] * invR;
        float var = stats[128 + c] * invR - mean * mean;
        float sc = g1[c] * rsqrtf(var + BN_EPS);
        ls_sc[p] = sc;
        ls_sh[p] = be1[c] - mean * sc;
    }
    __syncthreads();

    const int lane = threadIdx.x & 63;
    const int h = lane >> 5, t = lane & 31;
    const int wid = blockIdx.x * 4 + (threadIdx.x >> 6);
    const int nw = gridDim.x * 4;
    const int chunk = (N + nw - 1) / nw;
    const int v0 = wid * chunk;
    const int v1 = (v0 + chunk < N) ? v0 + chunk : N;

    const float sc0 = ls_sc[t * 4 + 0], sc1 = ls_sc[t * 4 + 1];
    const float sc2 = ls_sc[t * 4 + 2], sc3 = ls_sc[t * 4 + 3];
    const float sh0 = ls_sh[t * 4 + 0], sh1 = ls_sh[t * 4 + 1];
    const float sh2 = ls_sh[t * 4 + 2], sh3 = ls_sh[t * 4 + 3];

    for (int v = v0; v < v1; ++v) {
        const int cnt = CNTi[v];
        const int beg = OFF[v] - cnt;   // fill_k advanced OFF to end
        const short* base = T1p + (size_t)beg * 128 + t * 4;
        float a0 = 0.f, a1 = 0.f, a2 = 0.f, a3 = 0.f;
        int j = 0;
        for (; j + 4 <= cnt; j += 4) {
            u32x2 wA = ldnt_u2(base + (size_t)(j + h) * 128);
            u32x2 wB = ldnt_u2(base + (size_t)(j + 2 + h) * 128);
            a0 += selu_f(sc0 * bf2f((short)(wA[0] & 0xffff)) + sh0);
            a1 += selu_f(sc1 * bf2f((short)(wA[0] >> 16)) + sh1);
            a2 += selu_f(sc2 * bf2f((short)(wA[1] & 0xffff)) + sh2);
            a3 += selu_f(sc3 * bf2f((short)(wA[1] >> 16)) + sh3);
            a0 += selu_f(sc0 * bf2f((short)(wB[0] & 0xffff)) + sh0);
            a1 += selu_f(sc1 * bf2f((short)(wB[0] >> 16)) + sh1);
            a2 += selu_f(sc2 * bf2f((short)(wB[1] & 0xffff)) + sh2);
            a3 += selu_f(sc3 * bf2f((short)(wB[1] >> 16)) + sh3);
        }
        for (; j < cnt; j += 2) {
            if (j + h < cnt) {
                u32x2 w = ldnt_u2(base + (size_t)(j + h) * 128);
                a0 += selu_f(sc0 * bf2f((short)(w[0] & 0xffff)) + sh0);
                a1 += selu_f(sc1 * bf2f((short)(w[0] >> 16)) + sh1);
                a2 += selu_f(sc2 * bf2f((short)(w[1] & 0xffff)) + sh2);
                a3 += selu_f(sc3 * bf2f((short)(w[1] >> 16)) + sh3);
            }
        }
        a0 += __shfl_xor(a0, 32); a1 += __shfl_xor(a1, 32);
        a2 += __shfl_xor(a2, 32); a3 += __shfl_xor(a3, 32);
        if (h == 0) {
            const float inv = 1.0f / fmaxf((float)cnt, 1.0f);
            u32x2 o;
            o[0] = pack2(a0 * inv, a1 * inv);
            o[1] = pack2(a2 * inv, a3 * inv);
            *(u32x2*)(Aggm + (size_t)v * 128 + t * 4) = o;
        }
    }
}

// ---------------------------------------------------------------------------
// gemm3: T2p = packed([x, Aggm(packed), u[batch]] @ W2a' + (deg>0)*cb) ; fused stats
__global__ __launch_bounds__(256) void gemm3_node(
    const float* __restrict__ x, const short* __restrict__ Aggm,
    const float* __restrict__ u, const int* __restrict__ batch,
    const int* __restrict__ CNTi, const float* __restrict__ cb,
    const short* __restrict__ Wp, short* __restrict__ T2p,
    float* __restrict__ stats, int N)
{
    const int lane = threadIdx.x & 63, wave = threadIdx.x >> 6;
    const int m0 = blockIdx.x * 128 + wave * 32;
    const bool active = (m0 < N);   // N % 32 == 0
    const int lr = lane & 15, lg = lane >> 4;
    __shared__ float ls[256];
    ls[threadIdx.x] = 0.f;
    __syncthreads();

    if (active) {
        const int v0 = m0 + lr, v1 = m0 + 16 + lr;
        const float* u0 = u + (size_t)batch[v0] * 128;
        const float* u1 = u + (size_t)batch[v1] * 128;

        f32x4 acc[2][8];
#pragma unroll
        for (int t = 0; t < 2; ++t)
#pragma unroll
            for (int n = 0; n < 8; ++n) acc[t][n] = (f32x4){0.f, 0.f, 0.f, 0.f};

#pragma unroll
        for (int kb = 0; kb < 12; ++kb) {
            bfrag a0, a1;
            if (kb >= 4 && kb < 8) {
                a0 = *(const bfrag*)(Aggm + (size_t)v0 * 128 + (kb - 4) * 32 + lg * 8);
                a1 = *(const bfrag*)(Aggm + (size_t)v1 * 128 + (kb - 4) * 32 + lg * 8);
            } else {
                const float *p0, *p1;
                if (kb < 4) {
                    p0 = x + (size_t)v0 * 128 + kb * 32 + lg * 8;
                    p1 = x + (size_t)v1 * 128 + kb * 32 + lg * 8;
                } else {
                    p0 = u0 + (kb - 8) * 32 + lg * 8;
                    p1 = u1 + (kb - 8) * 32 + lg * 8;
                }
                a0 = load8f_bf(p0);
                a1 = load8f_bf(p1);
            }
            const short* wb = Wp + (size_t)kb * 4096;
#pragma unroll
            for (int n0 = 0; n0 < 8; ++n0) {
                bfrag b = *(const bfrag*)(wb + ((n0 * 16 + lr) * 4 + lg) * 8);
                acc[0][n0] = __builtin_amdgcn_mfma_f32_16x16x32_bf16(a0, b, acc[0][n0], 0, 0, 0);
                acc[1][n0] = __builtin_amdgcn_mfma_f32_16x16x32_bf16(a1, b, acc[1][n0], 0, 0, 0);
            }
        }
        // epilogue: + flag*cb, stats, packed store
        float cbl[8];
#pragma unroll
        for (int n0 = 0; n0 < 8; ++n0) cbl[n0] = cb[n0 * 16 + lr];
        float ps[8], qs[8];
#pragma unroll
        for (int n0 = 0; n0 < 8; ++n0) { ps[n0] = 0.f; qs[n0] = 0.f; }
#pragma unroll
        for (int t = 0; t < 2; ++t) {
            const int rbase = m0 + t * 16 + lg * 4;
            float fl[4];
#pragma unroll
            for (int r = 0; r < 4; ++r) fl[r] = (CNTi[rbase + r] > 0) ? 1.f : 0.f;
#pragma unroll
            for (int r = 0; r < 4; ++r) {
                bfrag o;
#pragma unroll
                for (int n0 = 0; n0 < 8; ++n0) {
                    float v = acc[t][n0][r] + fl[r] * cbl[n0];
                    ps[n0] += v; qs[n0] += v * v;
                    o[n0] = f2bf(v);
                }
                *(bfrag*)(T2p + (size_t)(rbase + r) * 128 + lr * 8) = o;
            }
        }
#pragma unroll
        for (int n0 = 0; n0 < 8; ++n0) {
            const int c = n0 * 16 + lr;
            float p = ps[n0], q = qs[n0];
            p += __shfl_xor(p, 16); p += __shfl_xor(p, 32);
            q += __shfl_xor(q, 16); q += __shfl_xor(q, 32);
            if (lg == 0) { atomicAdd(&ls[c], p); atomicAdd(&ls[128 + c], q); }
        }
    }
    __syncthreads();
    atomicAdd(&stats[threadIdx.x], ls[threadIdx.x]);
}

// Node GEMM2: out = selu(BN2(T2p)) @ W2b' + b2b   (f32 true-order output)
__global__ __launch_bounds__(256) void gemm4_node(
    const short* __restrict__ T2p, const float* __restrict__ stats,
    const float* __restrict__ g2, const float* __restrict__ be2,
    const short* __restrict__ Wp, const float* __restrict__ b2b,
    float* __restrict__ out, int N, float invR)
{
    __shared__ float ls_sc[128], ls_sh[128];
    if (threadIdx.x < 128) {
        int c = threadIdx.x;                     // true col
        float mean = stats[c] * invR;
        float var = stats[128 + c] * invR - mean * mean;
        float sc = g2[c] * rsqrtf(var + BN_EPS);
        ls_sc[c] = sc;
        ls_sh[c] = be2[c] - mean * sc;
    }
    __syncthreads();

    const int lane = threadIdx.x & 63, wave = threadIdx.x >> 6;
    const int m0 = blockIdx.x * 128 + wave * 32;
    if (m0 >= N) return;   // N % 32 == 0
    const int lr = lane & 15, lg = lane >> 4;
    const int e0 = m0 + lr, e1 = m0 + 16 + lr;

    f32x4 acc[2][8];
#pragma unroll
    for (int n0 = 0; n0 < 8; ++n0) {
        float bias = b2b[n0 * 16 + lr];
        acc[0][n0] = (f32x4){bias, bias, bias, bias};
        acc[1][n0] = (f32x4){bias, bias, bias, bias};
    }
#pragma unroll
    for (int kb = 0; kb < 4; ++kb) {
        // packed pos p = kb*32+lg*8+j  ->  true col j*16 + kb*4 + lg
        float scl[8], shf[8];
#pragma unroll
        for (int j = 0; j < 8; ++j) {
            int c = j * 16 + kb * 4 + lg;
            scl[j] = ls_sc[c];
            shf[j] = ls_sh[c];
        }
        bfrag r0 = *(const bfrag*)(T2p + (size_t)e0 * 128 + kb * 32 + lg * 8);
        bfrag r1 = *(const bfrag*)(T2p + (size_t)e1 * 128 + kb * 32 + lg * 8);
        bfrag a0, a1;
#pragma unroll
        for (int j = 0; j < 8; ++j) {
            a0[j] = f2bf(selu_f(bf2f(r0[j]) * scl[j] + shf[j]));
            a1[j] = f2bf(selu_f(bf2f(r1[j]) * scl[j] + shf[j]));
        }
        const short* wb = Wp + (size_t)kb * 4096;
#pragma unroll
        for (int n0 = 0; n0 < 8; ++n0) {
            bfrag b = *(const bfrag*)(wb + ((n0 * 16 + lr) * 4 + lg) * 8);
            acc[0][n0] = __builtin_amdgcn_mfma_f32_16x16x32_bf16(a0, b, acc[0][n0], 0, 0, 0);
            acc[1][n0] = __builtin_amdgcn_mfma_f32_16x16x32_bf16(a1, b, acc[1][n0], 0, 0, 0);
        }
    }
#pragma unroll
    for (int t = 0; t < 2; ++t) {
        const int rbase = m0 + t * 16 + lg * 4;
#pragma unroll
        for (int n0 = 0; n0 < 8; ++n0) {
            const int c = n0 * 16 + lr;
#pragma unroll
            for (int r = 0; r < 4; ++r)
                __builtin_nontemporal_store(acc[t][n0][r],
                    out + (size_t)(rbase + r) * 128 + c);
        }
    }
}

// ---------------------------------------------------------------------------
// Workspace layout (bytes):
//   0        Wp1x 32768  | 32768 Wp1e 16384 | 49152 Wp2a 98304 | 147456 Wp2b 32768
//   245760   cb 512
//   246272   stats1 1024 | 247296 stats2 1024
//   250368   CNTi 400000 | 650368 OFF 400000
//   1050368  BSUM 1024   | 1051392 BOFF 1024
//   1052416  SPOS 3200000
//   4252416  Aggm bf16 100000x128 (25600000)
//   29852416 Xap bf16 100000x128 (25600000)  [phase2: T2p overlays]
//   55452416 T1p bf16 800000x128 (204800000)  [CSR-sorted row order]
//   total: 260252416
// ---------------------------------------------------------------------------
extern "C" void kernel_launch(void* const* d_in, const int* in_sizes, int n_in,
                              void* d_out, int out_size, void* d_ws, size_t ws_size,
                              hipStream_t stream)
{
    const float* x   = (const float*)d_in[0];
    const float* ea  = (const float*)d_in[1];
    const float* u   = (const float*)d_in[2];
    const float* W1a = (const float*)d_in[3];
    // d_in[4] = b1a: cancels in BN1
    const float* g1  = (const float*)d_in[5];
    const float* be1 = (const float*)d_in[6];
    const float* W1b = (const float*)d_in[7];
    const float* b1b = (const float*)d_in[8];
    const float* W2a = (const float*)d_in[9];
    // d_in[10] = b2a: cancels in BN2
    const float* g2  = (const float*)d_in[11];
    const float* be2 = (const float*)d_in[12];
    const float* W2b = (const float*)d_in[13];
    const float* b2b = (const float*)d_in[14];
    const int* ei    = (const int*)d_in[15];
    const int* rowI  = ei;
    const int* colI  = ei + N_EDGES;
    const int* batch = (const int*)d_in[16];
    float* out = (float*)d_out;

    if (ws_size < 260252416ull) return;

    char* ws = (char*)d_ws;
    short* Wp1x   = (short*)(ws + 0);
    short* Wp1e   = (short*)(ws + 32768);
    short* Wp2a   = (short*)(ws + 49152);
    short* Wp2b   = (short*)(ws + 147456);
    float* cb     = (float*)(ws + 245760);
    float* stats1 = (float*)(ws + 246272);
    float* stats2 = (float*)(ws + 247296);
    int*   CNTi   = (int*)(ws + 250368);
    int*   OFF    = (int*)(ws + 650368);
    int*   BSUM   = (int*)(ws + 1050368);
    int*   BOFF   = (int*)(ws + 1051392);
    int*   SPOS   = (int*)(ws + 1052416);
    short* Aggm   = (short*)(ws + 4252416);
    short* Xap    = (short*)(ws + 29852416ull);
    short* T2p    = (short*)(ws + 29852416ull);   // overlays Xap (dead after gemm1n)
    short* T1p    = (short*)(ws + 55452416ull);

    hipMemsetAsync(stats1, 0, 2048, stream);      // stats1, stats2
    hipMemsetAsync(CNTi, 0, 400000, stream);

    // all weight prep + histogram: one kernel
    prep<<<353 + (N_EDGES + 255) / 256, 256, 0, stream>>>(
        W1a, W1b, b1b, W2a, W2b, Wp1x, Wp1e, Wp2a, Wp2b, cb, colI, CNTi, N_EDGES);

    // CSR scan + inverse-perm fill
    scan1<<<98, 1024, 0, stream>>>(CNTi, OFF, BSUM, N_NODES);
    scan2<<<1, 128, 0, stream>>>(BSUM, BOFF, 98);
    scan3<<<98, 1024, 0, stream>>>(OFF, BOFF, N_NODES);
    fill_k<<<(N_EDGES + 255) / 256, 256, 0, stream>>>(colI, OFF, SPOS, N_EDGES);

    // node-side half of edge layer 1
    gemmX<<<(N_NODES + 127) / 128, 256, 0, stream>>>(x, Wp1x, Xap, N_NODES);

    // edge layer 1 (natural read order, sorted write order) + stats
    gemm1n<<<2048, 256, 0, stream>>>(ea, rowI, SPOS, Wp1e, Xap, T1p, stats1, N_EDGES);

    // segmented selu-mean over bucket-contiguous T1p; BN1 inline
    segsel<<<2048, 256, 0, stream>>>(T1p, stats1, g1, be1, OFF, CNTi, Aggm,
                                     N_NODES, 1.0f / (float)N_EDGES);

    // node MLP
    gemm3_node<<<(N_NODES + 127) / 128, 256, 0, stream>>>(x, Aggm, u, batch, CNTi, cb,
                                                          Wp2a, T2p, stats2, N_NODES);
    gemm4_node<<<(N_NODES + 127) / 128, 256, 0, stream>>>(T2p, stats2, g2, be2, Wp2b, b2b,
                                                          out, N_NODES, 1.0f / (float)N_NODES);
}